// Round 18
// baseline (87.691 us; speedup 1.0000x reference)
//
#include <hip/hip_runtime.h>
#include <math.h>

#define BB 2
#define VV 5
#define CC 32
#define HH 128
#define WW 160
#define DD 32
#define HWp (HH*WW)          // 20480
#define NV (VV-1)            // 4 src views
#define PX 16                // pixels per block (divides WW)
#define MAXSLOT 18           // max x-table entries per (pixel,view)

// collapsed-PWL h2 tables
#define NKK 152
#define NSEG 153
#define NBND 154
#define NG 2048
#define SSC 128.f

// ---- workspace float offsets ----
#define OFF_RT   0
#define OFF_FEAT 512
#define OFF_SIM  (OFF_FEAT + VV*BB*HWp*CC)
#define OFF_AB   (OFF_SIM + BB*DD*HWp)               // A[153]@0, B[153]@160, bnd[154]@320, sidx 512w@480
#define OFF_FLAG (OFF_AB + 992)

// ---- output float offsets ----
#define OUT_DEPTH 0
#define OUT_CONF  (BB*HWp)
#define OUT_PROB  (2*BB*HWp)
#define OUT_COST  (OUT_PROB + BB*DD*HWp)
#define OUT_VW    (OUT_COST + BB*DD*HWp)

// ---- fused_sim LDS union layout ----
#define ZI(d,k)     smemU[(d)*17 + (k)]
#define DEP(d,k)    smemU[(d)*17 + (k)]
#define REF(p,c)    smemU[544 + (p)*36 + (c)]
#define GT(v,p,i)   smemU[1120 + ((v)*16 + (p))*18 + (i)]
#define AY0(v,p)    smemU[2272 + (v)*16 + (p)]
#define AY1(v,p)    smemU[2336 + (v)*16 + (p)]
#define IR0(v,p)    smemI[2400 + (v)*16 + (p)]
#define IR1(v,p)    smemI[2464 + (v)*16 + (p)]
#define IXB(v,p)    smemI[2528 + (v)*16 + (p)]
#define ISL(v,p)    smemI[2592 + (v)*16 + (p)]
#define BADF        smemI[2656]
#define SIMG(v,d,p) smemU[544 + (((v)*32 + (d))*17 + (p))]

// ---------------- setup body (block 0 of transpose kernel) ----------
__device__ void build_proj(const float* proj, int b, int v, double M[4][4]) {
    const float* E = proj + (((b*VV + v)*2 + 0)*16);
    const float* K = proj + (((b*VV + v)*2 + 1)*16);
    for (int r = 0; r < 3; r++)
        for (int c = 0; c < 4; c++) {
            double s = 0.0;
            for (int k = 0; k < 3; k++) s += (double)K[r*4+k] * (double)E[k*4+c];
            M[r][c] = s;
        }
    for (int c = 0; c < 4; c++) M[3][c] = (double)E[12+c];
}

__device__ void inv4(const double M[4][4], double out[4][4]) {
    double a[4][8];
    for (int i = 0; i < 4; i++)
        for (int j = 0; j < 4; j++) { a[i][j] = M[i][j]; a[i][4+j] = (i == j) ? 1.0 : 0.0; }
    for (int col = 0; col < 4; col++) {
        int piv = col; double best = fabs(a[col][col]);
        for (int r = col+1; r < 4; r++) if (fabs(a[r][col]) > best) { best = fabs(a[r][col]); piv = r; }
        if (piv != col) for (int j = 0; j < 8; j++) { double t = a[col][j]; a[col][j] = a[piv][j]; a[piv][j] = t; }
        double dinv = 1.0 / a[col][col];
        for (int j = 0; j < 8; j++) a[col][j] *= dinv;
        for (int r = 0; r < 4; r++) {
            if (r == col) continue;
            double f = a[r][col];
            for (int j = 0; j < 8; j++) a[r][j] -= f * a[col][j];
        }
    }
    for (int i = 0; i < 4; i++) for (int j = 0; j < 4; j++) out[i][j] = a[i][4+j];
}

__device__ void setup_body(const float* __restrict__ proj,
    const float* __restrict__ w0, const float* __restrict__ g0, const float* __restrict__ b0,
    const float* __restrict__ m0, const float* __restrict__ v0,
    const float* __restrict__ w1, const float* __restrict__ g1, const float* __restrict__ b1,
    const float* __restrict__ m1, const float* __restrict__ v1,
    const float* __restrict__ w2, const float* __restrict__ b2,
    float* __restrict__ ws, int t,
    float* __restrict__ prmL, float* __restrict__ kinkL, float* __restrict__ sortedK) {

    if (t < BB*NV) {
        int b = t / NV, v = 1 + (t % NV);
        double refM[4][4], inv[4][4], S[4][4];
        build_proj(proj, b, 0, refM);
        inv4(refM, inv);
        build_proj(proj, b, v, S);
        float* rt = ws + OFF_RT + (b*NV + (v-1))*12;
        for (int r = 0; r < 3; r++) {
            for (int c = 0; c < 3; c++) {
                double s = 0.0;
                for (int k = 0; k < 4; k++) s += S[r][k] * inv[k][c];
                rt[r*3 + c] = (float)s;
            }
            double s = 0.0;
            for (int k = 0; k < 4; k++) s += S[r][k] * inv[k][3];
            rt[9 + r] = (float)s;
        }
    }

    if (t < 16) {
        float sc = g0[t] / sqrtf(v0[t] + 1e-5f);
        prmL[t]      = w0[t] * sc;
        prmL[16 + t] = b0[t] - m0[t] * sc;
    }
    if (t >= 32 && t < 160) {
        int i = t - 32, q = i >> 4, o = i & 15;
        float sc = g1[q] / sqrtf(v1[q] + 1e-5f);
        prmL[32 + q*16 + o] = w1[q*16 + o] * sc;
    }
    if (t >= 160 && t < 168) {
        int q = t - 160;
        float sc = g1[q] / sqrtf(v1[q] + 1e-5f);
        prmL[160 + q] = b1[q] - m1[q] * sc;
        prmL[168 + q] = w2[q];
    }
    if (t == 176) prmL[176] = b2[0];
    __syncthreads();

    if (t < BB) {
        int ok = 1;
        for (int i = 0; i < NV; i++) {
            const float* ri = ws + OFF_RT + (t*NV + i)*12;
            ok &= (fabsf(ri[6])        < 1e-6f);
            ok &= (fabsf(ri[7])        < 1e-6f);
            ok &= (fabsf(ri[8] - 1.f)  < 1e-6f);
            ok &= (fabsf(ri[10])       < 1e-6f);
            ok &= (fabsf(ri[11])       < 1e-6f);
        }
        ws[OFF_FLAG + t] = ok ? 1.f : 0.f;
    }

    if (t < 16) {
        float a = prmL[t];
        kinkL[t] = (a != 0.f) ? (-prmL[16+t]/a) : 3.4e38f;
    }
    __syncthreads();
    if (t < 16) {
        float ki = kinkL[t]; int r = 0;
        for (int j = 0; j < 16; j++) {
            float kj = kinkL[j];
            r += (kj < ki) || (kj == ki && j < t) ? 1 : 0;
        }
        sortedK[r] = ki;
    }
    __syncthreads();
    if (t < 8*17) {
        int q = t / 17, j = t % 17;
        float lo = (j == 0)  ? -3.4e38f : sortedK[j-1];
        float hi = (j == 16) ?  3.4e38f : sortedK[j];
        bool loInf = (lo < -1e30f), hiInf = (hi > 1e30f);
        float rep;
        if (loInf && hiInf)      rep = 0.f;
        else if (loInf)          rep = hi - 1.f;
        else if (hiInf)          rep = lo + 1.f;
        else                     rep = 0.5f*(lo + hi);
        float alpha = 0.f, beta = prmL[160+q];
        for (int o = 0; o < 16; o++) {
            float a = prmL[o], c = prmL[16+o];
            if (fmaf(a, rep, c) > 0.f) {
                alpha += prmL[32+q*16+o]*a;
                beta  += prmL[32+q*16+o]*c;
            }
        }
        float z = 3.4e38f;
        if (alpha != 0.f) {
            float zz = -beta/alpha;
            if (zz > lo && zz < hi) z = zz;
        }
        kinkL[16 + t] = z;
    }
    __syncthreads();
    if (t < NKK) {
        float ki = kinkL[t]; int r = 0;
        for (int j = 0; j < NKK; j++) {
            float kj = kinkL[j];
            r += (kj < ki) || (kj == ki && j < t) ? 1 : 0;
        }
        sortedK[r] = ki;
    }
    __syncthreads();
    if (t == 0) ws[OFF_AB + 320 + 0] = -3.9e38f;
    if (t == 1) ws[OFF_AB + 320 + NKK + 1] = 3.9e38f;
    if (t < NKK) ws[OFF_AB + 320 + 1 + t] = sortedK[t];
    if (t < NSEG) {
        float lo = (t == 0)   ? -3.4e38f : sortedK[t-1];
        float hi = (t == NKK) ?  3.4e38f : sortedK[t];
        bool loInf = (lo < -1e30f), hiInf = (hi > 1e30f);
        float rep;
        if (loInf && hiInf)      rep = 0.f;
        else if (loInf)          rep = hi - 1.f;
        else if (hiInf)          rep = lo + 1.f;
        else                     rep = 0.5f*(lo + hi);
        float h0[16]; bool act0[16];
        for (int o = 0; o < 16; o++) {
            float h = fmaf(prmL[o], rep, prmL[16+o]);
            act0[o] = (h > 0.f);
            h0[o] = fmaxf(h, 0.f);
        }
        float A = 0.f, h2m = prmL[176];
        for (int q = 0; q < 8; q++) {
            float a1 = prmL[160+q], alq = 0.f;
            for (int o = 0; o < 16; o++) {
                a1 += prmL[32+q*16+o]*h0[o];
                if (act0[o]) alq += prmL[32+q*16+o]*prmL[o];
            }
            if (a1 > 0.f) { h2m += prmL[168+q]*a1; A += prmL[168+q]*alq; }
        }
        ws[OFF_AB + t]       = A;
        ws[OFF_AB + 160 + t] = h2m - A*rep;
    }
    for (int i4 = t; i4 < 512; i4 += 256) {
        unsigned word = 0;
        for (int kk = 0; kk < 4; kk++) {
            float si = -8.f + (float)(i4*4 + kk) * (1.f/SSC);
            int cnt = 0;
            for (int j = 0; j < NKK; j++) cnt += (sortedK[j] <= si) ? 1 : 0;
            word |= ((unsigned)cnt) << (8*kk);
        }
        ws[OFF_AB + 480 + i4] = __uint_as_float(word);
    }
}

// ---------------- transpose (+ setup in block 0) ----------------
__global__ __launch_bounds__(256) void transpose_setup_kernel(
    const float* __restrict__ fea, float* __restrict__ featT,
    const float* __restrict__ proj,
    const float* __restrict__ w0, const float* __restrict__ g0, const float* __restrict__ b0,
    const float* __restrict__ m0, const float* __restrict__ v0,
    const float* __restrict__ w1, const float* __restrict__ g1, const float* __restrict__ b1,
    const float* __restrict__ m1, const float* __restrict__ v1,
    const float* __restrict__ w2, const float* __restrict__ b2,
    float* __restrict__ ws) {
    __shared__ float prmL[177];
    __shared__ float kinkL[NKK];
    __shared__ float sortedK[NKK];
    if (blockIdx.x == 0)
        setup_body(proj, w0, g0, b0, m0, v0, w1, g1, b1, m1, v1, w2, b2,
                   ws, threadIdx.x, prmL, kinkL, sortedK);

    int t = blockIdx.x*256 + threadIdx.x;
    int w = t % WW;
    int h = (t / WW) % HH;
    int b = (t / (WW*HH)) % BB;
    int v = t / (WW*HH*BB);
    const float* src = fea + (size_t)((v*BB + b)*CC) * HWp + h*WW + w;
    float* dst = featT + (size_t)((v*BB + b)*HWp + h*WW + w) * CC;
    #pragma unroll
    for (int c = 0; c < CC; c += 4) {
        float4 q;
        q.x = src[(c+0)*HWp];
        q.y = src[(c+1)*HWp];
        q.z = src[(c+2)*HWp];
        q.w = src[(c+3)*HWp];
        *reinterpret_cast<float4*>(dst + c) = q;
    }
}

__device__ __forceinline__ float half_max(float v) {
    v = fmaxf(v, __shfl_xor(v, 1));
    v = fmaxf(v, __shfl_xor(v, 2));
    v = fmaxf(v, __shfl_xor(v, 4));
    v = fmaxf(v, __shfl_xor(v, 8));
    v = fmaxf(v, __shfl_xor(v, 16));
    return v;
}

__device__ __forceinline__ float dot32(const float* __restrict__ col,
                                       const float* __restrict__ refp) {
    float acc = 0.f;
    #pragma unroll
    for (int c = 0; c < CC; c += 4) {
        float4 a = *reinterpret_cast<const float4*>(col + c);
        float4 r = *reinterpret_cast<const float4*>(refp + c);
        acc = fmaf(a.w, r.w, fmaf(a.z, r.z, fmaf(a.y, r.y, fmaf(a.x, r.x, acc))));
    }
    return acc;
}

// two independent column dots with interleaved loads (memory-level parallelism)
__device__ __forceinline__ void dot32x2(const float* __restrict__ colA,
                                        const float* __restrict__ colB,
                                        const float* __restrict__ refp,
                                        float& accA, float& accB) {
    accA = 0.f; accB = 0.f;
    #pragma unroll
    for (int c = 0; c < CC; c += 4) {
        float4 a = *reinterpret_cast<const float4*>(colA + c);
        float4 bq = *reinterpret_cast<const float4*>(colB + c);
        float4 r = *reinterpret_cast<const float4*>(refp + c);
        accA = fmaf(a.w, r.w, fmaf(a.z, r.z, fmaf(a.y, r.y, fmaf(a.x, r.x, accA))));
        accB = fmaf(bq.w, r.w, fmaf(bq.z, r.z, fmaf(bq.y, r.y, fmaf(bq.x, r.x, accB))));
    }
}

// phase-B body (lane layout: d2 = lane&31)
__device__ __forceinline__ void mlp_out(
    float s0, float s1, float s2, float s3,
    int d2, int b, int p,
    const float* __restrict__ AL, const float* __restrict__ BL2,
    const float* __restrict__ BNDL, const unsigned char* __restrict__ SIDX,
    float* __restrict__ out, float* __restrict__ simout) {
    float sv[NV] = {s0, s1, s2, s3};
    float vw[NV];
    #pragma unroll
    for (int v = 0; v < NV; v++) {
        float s = sv[v];
        float u = fmaf(s, SSC, 1024.f);
        int ic = (int)fminf(fmaxf(u, 0.f), 2047.f);
        int seg = SIDX[ic];
        while (s >= BNDL[seg+1]) seg++;
        while (seg > 0 && s < BNDL[seg]) seg--;
        float h2v = fmaf(AL[seg], s, BL2[seg]);
        float m = half_max(h2v);
        vw[v] = 1.f/(1.f + __expf(-m));
    }

    if (d2 == 0) out[OUT_VW + (b*NV + 0)*HWp + p] = vw[0];
    if (d2 == 1) out[OUT_VW + (b*NV + 1)*HWp + p] = vw[1];
    if (d2 == 2) out[OUT_VW + (b*NV + 2)*HWp + p] = vw[2];
    if (d2 == 3) out[OUT_VW + (b*NV + 3)*HWp + p] = vw[3];

    float wsum = 1e-5f + vw[0] + vw[1] + vw[2] + vw[3];
    float ssum = s0*vw[0] + s1*vw[1] + s2*vw[2] + s3*vw[3];
    simout[(b*DD + d2)*HWp + p] = ssum / wsum;
}

// general-path x-side tap pair
__device__ __forceinline__ float tap_blend(
    const float* __restrict__ vbv, int sub8, float sx,
    float ay0, float ay1, int r0, int r1,
    float4 rva, float4 rvb) {
    float x0f = floorf(sx);
    float wx1 = sx - x0f;
    float wx0 = 1.f - wx1;
    int xi0 = (int)x0f, xi1 = xi0 + 1;
    float ax0 = ((unsigned)xi0 < WW) ? wx0 : 0.f;
    float ax1 = ((unsigned)xi1 < WW) ? wx1 : 0.f;
    int xc0 = min(max(xi0, 0), WW-1);
    int xc1 = min(max(xi1, 0), WW-1);
    float w00 = ax0*ay0, w01 = ax1*ay0;
    const float* q00 = vbv + (((r0 + xc0) << 5) + sub8);
    const float* q01 = vbv + (((r0 + xc1) << 5) + sub8);
    float4 t00a = *reinterpret_cast<const float4*>(q00);
    float4 t00b = *reinterpret_cast<const float4*>(q00 + 4);
    float4 t01a = *reinterpret_cast<const float4*>(q01);
    float4 t01b = *reinterpret_cast<const float4*>(q01 + 4);

    float blx = fmaf(w01, t01a.x, w00*t00a.x);
    float bly = fmaf(w01, t01a.y, w00*t00a.y);
    float blz = fmaf(w01, t01a.z, w00*t00a.z);
    float blw = fmaf(w01, t01a.w, w00*t00a.w);
    float acc = fmaf(rva.w,blw, fmaf(rva.z,blz, fmaf(rva.y,bly, rva.x*blx)));
    blx = fmaf(w01, t01b.x, w00*t00b.x);
    bly = fmaf(w01, t01b.y, w00*t00b.y);
    blz = fmaf(w01, t01b.z, w00*t00b.z);
    blw = fmaf(w01, t01b.w, w00*t00b.w);
    acc = fmaf(rvb.w,blw, fmaf(rvb.z,blz, fmaf(rvb.y,bly, fmaf(rvb.x,blx, acc))));

    if (ay1 != 0.f) {
        float w10 = ax0*ay1, w11 = ax1*ay1;
        const float* q10 = vbv + (((r1 + xc0) << 5) + sub8);
        const float* q11 = vbv + (((r1 + xc1) << 5) + sub8);
        float4 t10a = *reinterpret_cast<const float4*>(q10);
        float4 t10b = *reinterpret_cast<const float4*>(q10 + 4);
        float4 t11a = *reinterpret_cast<const float4*>(q11);
        float4 t11b = *reinterpret_cast<const float4*>(q11 + 4);
        float cx = fmaf(w11, t11a.x, w10*t10a.x);
        float cy = fmaf(w11, t11a.y, w10*t10a.y);
        float cz = fmaf(w11, t11a.z, w10*t10a.z);
        float cw = fmaf(w11, t11a.w, w10*t10a.w);
        acc = fmaf(rva.w,cw, fmaf(rva.z,cz, fmaf(rva.y,cy, fmaf(rva.x,cx, acc))));
        cx = fmaf(w11, t11b.x, w10*t10b.x);
        cy = fmaf(w11, t11b.y, w10*t10b.y);
        cz = fmaf(w11, t11b.z, w10*t10b.z);
        cw = fmaf(w11, t11b.w, w10*t10b.w);
        acc = fmaf(rvb.w,cw, fmaf(rvb.z,cz, fmaf(rvb.y,cy, fmaf(rvb.x,cx, acc))));
    }
    return acc;
}

// ---------------- fused warp + sim + PWL-MLP + view aggregation ----------------
__global__ __launch_bounds__(256) void fused_sim_kernel(
    const float* __restrict__ featT, const float* __restrict__ rtAll,
    const float* __restrict__ tb,
    const float* __restrict__ flagG,
    const float* __restrict__ depthv,
    float* __restrict__ simout, float* __restrict__ out) {
    __shared__ __align__(16) float smemU[2720];
    __shared__ float AL[NSEG];
    __shared__ float BL2[NSEG];
    __shared__ float BNDL[NBND];
    __shared__ unsigned SIDXW[512];
    int* smemI = (int*)smemU;
    const unsigned char* SIDX = (const unsigned char*)SIDXW;

    int t = threadIdx.x;
    int b = blockIdx.y;
    int pbase = blockIdx.x * PX;
    int hi  = pbase / WW;
    int wi0 = pbase % WW;
    float fy = (float)hi;

    bool fast = (flagG[b] != 0.f);

    // ---- staging ----
    {
        int di = t >> 4, k = t & 15;
        float dep0 = depthv[(b*DD + di)*HWp + pbase + k];
        float dep1 = depthv[(b*DD + di + 16)*HWp + pbase + k];
        if (fast) {
            ZI(di, k)    = __builtin_amdgcn_rcpf(dep0);
            ZI(di+16, k) = __builtin_amdgcn_rcpf(dep1);
            if (t < 128) {      // ref features via float4: p = t>>3, c4 = (t&7)*4
                int p = t >> 3, c4 = (t & 7) * 4;
                float4 rq = *reinterpret_cast<const float4*>(
                    featT + (size_t)(b*HWp + pbase + p)*CC + c4);
                *reinterpret_cast<float4*>(&REF(p, c4)) = rq;
            }
        } else {
            DEP(di, k)    = dep0;
            DEP(di+16, k) = dep1;
        }
        if (t < NSEG) { AL[t] = tb[t]; BL2[t] = tb[160 + t]; }
        if (t < NBND) BNDL[t] = tb[320 + t];
        SIDXW[t]       = __float_as_uint(tb[480 + t]);
        SIDXW[t + 256] = __float_as_uint(tb[480 + 256 + t]);
        if (t == 0 && fast) BADF = 0;
    }
    __syncthreads();

    float rc[NV][12];
    #pragma unroll
    for (int v = 0; v < NV; v++)
        #pragma unroll
        for (int j = 0; j < 12; j++)
            rc[v][j] = rtAll[(b*NV + v)*12 + j];
    float bx0[NV], by0[NV], bz0[NV];
    #pragma unroll
    for (int v = 0; v < NV; v++) {
        bx0[v] = fmaf((float)wi0, rc[v][0], fmaf(fy, rc[v][1], rc[v][2]));
        by0[v] = fmaf((float)wi0, rc[v][3], fmaf(fy, rc[v][4], rc[v][5]));
        bz0[v] = fmaf((float)wi0, rc[v][6], fmaf(fy, rc[v][7], rc[v][8]));
    }

    bool needRestage = false;
    if (fast) {
        // ---- step 1: zi-range once per pixel-phase; per-view range analytic ----
        int p_loc = t >> 5, d = t & 31;
        for (int ph = 0; ph < 2; ph++) {
            int p = ph*8 + p_loc;
            float zi = ZI(d, p);
            float mnz = zi, mxz = zi;
            #pragma unroll
            for (int off = 1; off <= 16; off <<= 1) {
                mnz = fminf(mnz, __shfl_xor(mnz, off));
                mxz = fmaxf(mxz, __shfl_xor(mxz, off));
            }
            if (d == 0) {
                float fk = (float)p;
                #pragma unroll
                for (int v = 0; v < NV; v++) {
                    float bx = fmaf(fk, rc[v][0], bx0[v]);
                    float t0c = rc[v][9];
                    // sx linear in zi -> extremes at zi extremes (exact/monotone)
                    float sxa = fmaf(t0c, mnz, bx);
                    float sxb = fmaf(t0c, mxz, bx);
                    float mn = fminf(sxa, sxb), mx = fmaxf(sxa, sxb);
                    float by = fmaf(fk, rc[v][3], by0[v]);
                    float sy = by;
                    float sny = rintf(sy);
                    sy = (fabsf(sy - sny) < 1e-4f) ? sny : sy;
                    float y0f = floorf(sy);
                    float wy1 = sy - y0f, wy0 = 1.f - wy1;
                    int yi0 = (int)y0f, yi1 = yi0 + 1;
                    AY0(v, p) = ((unsigned)yi0 < HH) ? wy0 : 0.f;
                    AY1(v, p) = ((unsigned)yi1 < HH) ? wy1 : 0.f;
                    IR0(v, p) = min(max(yi0, 0), HH-1)*WW;
                    IR1(v, p) = min(max(yi1, 0), HH-1)*WW;
                    bool finite = (mn > -1e9f) && (mx < 1e9f) && (mn == mn) && (mx == mx);
                    int xb = finite ? (int)floorf(mn) : 0;
                    int slots = finite ? ((int)floorf(mx) - xb + 2) : MAXSLOT + 1;
                    IXB(v, p) = xb;
                    ISL(v, p) = slots;
                    if (slots > MAXSLOT) BADF = 1;
                }
            }
        }
        __syncthreads();
        if (BADF) { fast = false; needRestage = true; }
    }

    if (fast) {
        // ---- step 2: all-view dot tables, dual-slot unrolled ----
        {
            int v2 = t & 3, p2 = (t >> 2) & 15, i0 = t >> 6;
            float ay0 = AY0(v2, p2), ay1 = AY1(v2, p2);
            int r0 = IR0(v2, p2), r1 = IR1(v2, p2);
            int xb = IXB(v2, p2), slots = ISL(v2, p2);
            const float* vbv = featT + (size_t)(((v2+1)*BB + b)*HWp)*CC;
            const float* refp = &REF(p2, 0);
            float sc = (1.f/(float)CC);
            for (int i2 = i0; i2 < slots; i2 += 8) {
                int j2 = i2 + 4;
                int xcA = min(max(xb + i2, 0), WW-1);
                int xcB = min(max(xb + j2, 0), WW-1);   // clamped; safe if j2>=slots
                float gA, gB;
                dot32x2(vbv + ((r0 + xcA) << 5), vbv + ((r0 + xcB) << 5), refp, gA, gB);
                gA *= ay0; gB *= ay0;
                if (ay1 != 0.f) {
                    float hA, hB;
                    dot32x2(vbv + ((r1 + xcA) << 5), vbv + ((r1 + xcB) << 5), refp, hA, hB);
                    gA = fmaf(ay1, hA, gA);
                    gB = fmaf(ay1, hB, gB);
                }
                GT(v2, p2, i2) = gA * sc;
                if (j2 < slots) GT(v2, p2, j2) = gB * sc;
            }
        }
        __syncthreads();
        // ---- step 3 fused with phase B ----
        {
            int p_loc = t >> 5, d = t & 31;
            for (int ph = 0; ph < 2; ph++) {
                int p = ph*8 + p_loc;
                float fk = (float)p;
                float zi = ZI(d, p);
                float sv[NV];
                #pragma unroll
                for (int v = 0; v < NV; v++) {
                    float bx = fmaf(fk, rc[v][0], bx0[v]);
                    float sx = fmaf(rc[v][9], zi, bx);
                    float x0f = floorf(sx);
                    float wx1 = sx - x0f, wx0 = 1.f - wx1;
                    int xi0 = (int)x0f, xi1 = xi0 + 1;
                    float ax0 = ((unsigned)xi0 < WW) ? wx0 : 0.f;
                    float ax1 = ((unsigned)xi1 < WW) ? wx1 : 0.f;
                    int ii = xi0 - IXB(v, p);
                    float g0 = GT(v, p, ii);
                    float g1 = GT(v, p, ii+1);
                    sv[v] = fmaf(ax0, g0, ax1*g1);
                }
                mlp_out(sv[0], sv[1], sv[2], sv[3], d, b, pbase + p,
                        AL, BL2, BNDL, SIDX, out, simout);
            }
        }
        return;
    }

    // ---------------- general path ----------------
    if (needRestage) {
        int di = t >> 4, k = t & 15;
        DEP(di, k)    = depthv[(b*DD + di)*HWp + pbase + k];
        DEP(di+16, k) = depthv[(b*DD + di + 16)*HWp + pbase + k];
        __syncthreads();
    }
    {
        int sub = t & 3;
        int dB  = (t >> 2) & 31;
        int kk  = t >> 7;
        int sub8 = sub*8;
        #pragma unroll 2
        for (int j = 0; j < PX/2; j++) {
            int kpix = j*2 + kk;
            int p = pbase + kpix;
            float fk = (float)kpix;
            float depth = DEP(dB, kpix);
            const float* refp = featT + (size_t)(b*HWp + p)*CC + sub8;
            float4 rva = *reinterpret_cast<const float4*>(refp);
            float4 rvb = *reinterpret_cast<const float4*>(refp + 4);

            #pragma unroll
            for (int v = 0; v < NV; v++) {
                float bx = fmaf(fk, rc[v][0], bx0[v]);
                float by = fmaf(fk, rc[v][3], by0[v]);
                float bz = fmaf(fk, rc[v][6], bz0[v]);
                float px = fmaf(bx, depth, rc[v][9]);
                float py = fmaf(by, depth, rc[v][10]);
                float pz = fmaf(bz, depth, rc[v][11]);
                float zi = __builtin_amdgcn_rcpf(pz);
                float sx = px * zi, sy = py * zi;
                float sny = rintf(sy);
                sy = (fabsf(sy - sny) < 1e-4f) ? sny : sy;
                float y0f = floorf(sy);
                float wy1 = sy - y0f, wy0 = 1.f - wy1;
                int yi0 = (int)y0f, yi1 = yi0 + 1;
                float ay0 = ((unsigned)yi0 < HH) ? wy0 : 0.f;
                float ay1 = ((unsigned)yi1 < HH) ? wy1 : 0.f;
                int yc0 = min(max(yi0, 0), HH-1);
                int yc1 = min(max(yi1, 0), HH-1);
                int r0 = yc0*WW, r1 = yc1*WW;
                const float* vbv = featT + (size_t)(((v+1)*BB + b)*HWp)*CC;
                float acc = tap_blend(vbv, sub8, sx, ay0, ay1, r0, r1, rva, rvb);
                acc += __shfl_xor(acc, 1);
                acc += __shfl_xor(acc, 2);
                if (sub == 0) SIMG(v, dB, kpix) = acc * (1.f/(float)CC);
            }
        }
        __syncthreads();

        int p8 = t >> 5;
        int d2 = t & 31;
        #pragma unroll
        for (int pi = 0; pi < PX/8; pi++) {
            int pidx = pi*8 + p8;
            mlp_out(SIMG(0, d2, pidx), SIMG(1, d2, pidx),
                    SIMG(2, d2, pidx), SIMG(3, d2, pidx),
                    d2, b, pbase + pidx, AL, BL2, BNDL, SIDX, out, simout);
        }
    }
}

// ---------------- fused 3x3x3 conv + softmax/argmax ----------------
__global__ __launch_bounds__(256) void convsm_kernel(
    const float* __restrict__ sim, const float* __restrict__ rw,
    const float* __restrict__ rb, const float* __restrict__ depthv,
    float* __restrict__ out) {
    __shared__ float tile[34*121 + 7];
    int t = threadIdx.x;
    int tw = blockIdx.x * 8;
    int th = blockIdx.y * 8;
    int b  = blockIdx.z;

    for (int i = t; i < 34*120; i += 256) {
        int e = i / 120; int rem = i % 120;
        int h = rem / 12, w = rem % 12;
        int gd = e - 1, gh = th + h - 1, gw = tw + w - 1;
        float v = 0.f;
        if (w < 10 && gd >= 0 && gd < DD && (unsigned)gh < HH && (unsigned)gw < WW)
            v = sim[((b*DD + gd)*HH + gh)*WW + gw];
        tile[e*121 + rem] = v;
    }
    __syncthreads();

    float wk[27];
    #pragma unroll
    for (int i = 0; i < 27; i++) wk[i] = rw[i];
    float bias = rb[0];

    int p  = t >> 2, dq = t & 3;
    int ph = p >> 3, pw = p & 7;
    int d0 = dq * 8;

    float cost[8];
    #pragma unroll
    for (int j = 0; j < 8; j++) cost[j] = bias;
    #pragma unroll
    for (int e = 0; e < 10; e++) {
        int el = d0 + e;
        float s0 = 0.f, s1 = 0.f, s2 = 0.f;
        #pragma unroll
        for (int kh = 0; kh < 3; kh++) {
            #pragma unroll
            for (int kw = 0; kw < 3; kw++) {
                float x = tile[el*121 + (ph+kh)*12 + (pw+kw)];
                s0 = fmaf(wk[0*9 + kh*3 + kw], x, s0);
                s1 = fmaf(wk[1*9 + kh*3 + kw], x, s1);
                s2 = fmaf(wk[2*9 + kh*3 + kw], x, s2);
            }
        }
        if (e < 8)            cost[e]   += s0;
        if (e >= 1 && e <= 8) cost[e-1] += s1;
        if (e >= 2)           cost[e-2] += s2;
    }

    int pg = (th + ph)*WW + (tw + pw);
    #pragma unroll
    for (int j = 0; j < 8; j++)
        out[OUT_COST + (b*DD + d0 + j)*HWp + pg] = cost[j];

    float m = cost[0]; int mi = d0;
    #pragma unroll
    for (int j = 1; j < 8; j++) { if (cost[j] > m) { m = cost[j]; mi = d0 + j; } }
    #pragma unroll
    for (int off = 1; off <= 2; off <<= 1) {
        float m2 = __shfl_xor(m, off);
        int  i2 = __shfl_xor(mi, off);
        if (m2 > m || (m2 == m && i2 < mi)) { m = m2; mi = i2; }
    }
    float sum = 0.f;
    float e8[8];
    #pragma unroll
    for (int j = 0; j < 8; j++) { e8[j] = __expf(cost[j] - m); sum += e8[j]; }
    #pragma unroll
    for (int off = 1; off <= 2; off <<= 1) sum += __shfl_xor(sum, off);
    float inv = 1.f / sum;
    #pragma unroll
    for (int j = 0; j < 8; j++)
        out[OUT_PROB + (b*DD + d0 + j)*HWp + pg] = e8[j] * inv;
    if (dq == 0) {
        out[OUT_DEPTH + b*HWp + pg] = depthv[(b*DD + mi)*HWp + pg];
        out[OUT_CONF  + b*HWp + pg] = inv;
    }
}

extern "C" void kernel_launch(void* const* d_in, const int* in_sizes, int n_in,
                              void* d_out, int out_size, void* d_ws, size_t ws_size,
                              hipStream_t stream) {
    const float* features = (const float*)d_in[0];
    const float* proj     = (const float*)d_in[1];
    const float* depthv   = (const float*)d_in[2];
    const float* w0 = (const float*)d_in[4];
    const float* g0 = (const float*)d_in[5];
    const float* b0 = (const float*)d_in[6];
    const float* m0 = (const float*)d_in[7];
    const float* v0 = (const float*)d_in[8];
    const float* w1 = (const float*)d_in[9];
    const float* g1 = (const float*)d_in[10];
    const float* b1 = (const float*)d_in[11];
    const float* m1 = (const float*)d_in[12];
    const float* v1 = (const float*)d_in[13];
    const float* w2 = (const float*)d_in[14];
    const float* b2 = (const float*)d_in[15];
    const float* rw = (const float*)d_in[16];
    const float* rb = (const float*)d_in[17];
    float* out = (float*)d_out;
    float* ws  = (float*)d_ws;

    transpose_setup_kernel<<<VV*BB*HWp/256, 256, 0, stream>>>(
        features, ws + OFF_FEAT, proj,
        w0, g0, b0, m0, v0, w1, g1, b1, m1, v1, w2, b2, ws);

    fused_sim_kernel<<<dim3(HWp/PX, BB), 256, 0, stream>>>(
        ws + OFF_FEAT, ws + OFF_RT, ws + OFF_AB,
        ws + OFF_FLAG, depthv, ws + OFF_SIM, out);

    convsm_kernel<<<dim3(WW/8, HH/8, BB), 256, 0, stream>>>(
        ws + OFF_SIM, rw, rb, depthv, out);
}

// Round 19
// 77.534 us; speedup vs baseline: 1.1310x; 1.1310x over previous
//
#include <hip/hip_runtime.h>
#include <math.h>

#define BB 2
#define VV 5
#define CC 32
#define HH 128
#define WW 160
#define DD 32
#define HWp (HH*WW)          // 20480
#define NV (VV-1)            // 4 src views
#define PX 16                // pixels per block (divides WW)
#define MAXSLOT 18           // max x-table entries per (pixel,view)

// ---- workspace float offsets ----
#define OFF_RT   0                                   // B*NV*12 = 96
#define OFF_PRM  96                                  // 177 net params
#define OFF_FEAT 512                                 // f32 features V*B*HW*C
#define OFF_SIM  (OFF_FEAT + VV*BB*HWp*CC)           // B*D*HW similarity
#define OFF_T    (OFF_SIM + BB*DD*HWp)               // 16 sorted kinks
#define OFF_TAB  (OFF_T + 16)                        // 17*16 segment table
#define OFF_FLAG (OFF_TAB + 17*16)                   // BB fast-geometry flags

// ---- output float offsets ----
#define OUT_DEPTH 0
#define OUT_CONF  (BB*HWp)
#define OUT_PROB  (2*BB*HWp)
#define OUT_COST  (OUT_PROB + BB*DD*HWp)
#define OUT_VW    (OUT_COST + BB*DD*HWp)

// ---- fused_sim LDS union layout (floats into smemU[2720]) ----
#define ZI(d,k)     smemU[(d)*17 + (k)]
#define DEP(d,k)    smemU[(d)*17 + (k)]
#define REF(p,c)    smemU[544 + (p)*36 + (c)]
#define GT(v,p,i)   smemU[1120 + ((v)*16 + (p))*18 + (i)]
#define AY0(v,p)    smemU[2272 + (v)*16 + (p)]
#define AY1(v,p)    smemU[2336 + (v)*16 + (p)]
#define IR0(v,p)    smemI[2400 + (v)*16 + (p)]
#define IR1(v,p)    smemI[2464 + (v)*16 + (p)]
#define IXB(v,p)    smemI[2528 + (v)*16 + (p)]
#define ISL(v,p)    smemI[2592 + (v)*16 + (p)]
#define BADF        smemI[2656]
#define SIMG(v,d,p) smemU[544 + (((v)*32 + (d))*17 + (p))]

// ---------------- setup body (runs in block 0 of transpose kernel) ----------
__device__ void build_proj(const float* proj, int b, int v, double M[4][4]) {
    const float* E = proj + (((b*VV + v)*2 + 0)*16);
    const float* K = proj + (((b*VV + v)*2 + 1)*16);
    for (int r = 0; r < 3; r++)
        for (int c = 0; c < 4; c++) {
            double s = 0.0;
            for (int k = 0; k < 3; k++) s += (double)K[r*4+k] * (double)E[k*4+c];
            M[r][c] = s;
        }
    for (int c = 0; c < 4; c++) M[3][c] = (double)E[12+c];
}

__device__ void inv4(const double M[4][4], double out[4][4]) {
    double a[4][8];
    for (int i = 0; i < 4; i++)
        for (int j = 0; j < 4; j++) { a[i][j] = M[i][j]; a[i][4+j] = (i == j) ? 1.0 : 0.0; }
    for (int col = 0; col < 4; col++) {
        int piv = col; double best = fabs(a[col][col]);
        for (int r = col+1; r < 4; r++) if (fabs(a[r][col]) > best) { best = fabs(a[r][col]); piv = r; }
        if (piv != col) for (int j = 0; j < 8; j++) { double t = a[col][j]; a[col][j] = a[piv][j]; a[piv][j] = t; }
        double dinv = 1.0 / a[col][col];
        for (int j = 0; j < 8; j++) a[col][j] *= dinv;
        for (int r = 0; r < 4; r++) {
            if (r == col) continue;
            double f = a[r][col];
            for (int j = 0; j < 8; j++) a[r][j] -= f * a[col][j];
        }
    }
    for (int i = 0; i < 4; i++) for (int j = 0; j < 4; j++) out[i][j] = a[i][4+j];
}

__device__ void setup_body(const float* __restrict__ proj,
    const float* __restrict__ w0, const float* __restrict__ g0, const float* __restrict__ b0,
    const float* __restrict__ m0, const float* __restrict__ v0,
    const float* __restrict__ w1, const float* __restrict__ g1, const float* __restrict__ b1,
    const float* __restrict__ m1, const float* __restrict__ v1,
    const float* __restrict__ w2, const float* __restrict__ b2,
    float* __restrict__ ws, int t,
    float* __restrict__ prmL, float* __restrict__ TL) {

    if (t < BB*NV) {
        int b = t / NV, v = 1 + (t % NV);
        double refM[4][4], inv[4][4], S[4][4];
        build_proj(proj, b, 0, refM);
        inv4(refM, inv);
        build_proj(proj, b, v, S);
        float* rt = ws + OFF_RT + (b*NV + (v-1))*12;
        for (int r = 0; r < 3; r++) {
            for (int c = 0; c < 3; c++) {
                double s = 0.0;
                for (int k = 0; k < 4; k++) s += S[r][k] * inv[k][c];
                rt[r*3 + c] = (float)s;
            }
            double s = 0.0;
            for (int k = 0; k < 4; k++) s += S[r][k] * inv[k][3];
            rt[9 + r] = (float)s;
        }
    }

    if (t < 16) {
        float sc = g0[t] / sqrtf(v0[t] + 1e-5f);
        prmL[t]      = w0[t] * sc;
        prmL[16 + t] = b0[t] - m0[t] * sc;
    }
    if (t >= 32 && t < 160) {
        int i = t - 32, q = i >> 4, o = i & 15;
        float sc = g1[q] / sqrtf(v1[q] + 1e-5f);
        prmL[32 + q*16 + o] = w1[q*16 + o] * sc;
    }
    if (t >= 160 && t < 168) {
        int q = t - 160;
        float sc = g1[q] / sqrtf(v1[q] + 1e-5f);
        prmL[160 + q] = b1[q] - m1[q] * sc;
        prmL[168 + q] = w2[q];
    }
    if (t == 176) prmL[176] = b2[0];
    __syncthreads();

    // fast-geometry detection (pz = depth, sy depth-independent)
    if (t < BB) {
        int ok = 1;
        for (int i = 0; i < NV; i++) {
            const float* ri = ws + OFF_RT + (t*NV + i)*12;
            ok &= (fabsf(ri[6])        < 1e-6f);
            ok &= (fabsf(ri[7])        < 1e-6f);
            ok &= (fabsf(ri[8] - 1.f)  < 1e-6f);
            ok &= (fabsf(ri[10])       < 1e-6f);
            ok &= (fabsf(ri[11])       < 1e-6f);
        }
        ws[OFF_FLAG + t] = ok ? 1.f : 0.f;
    }

    if (t == 0) {
        float tmp[16]; int nk = 0;
        for (int o = 0; o < 16; o++) {
            float a = prmL[o];
            if (a != 0.f) tmp[nk++] = -prmL[16+o] / a;
        }
        for (int i = 1; i < nk; i++) {
            float key = tmp[i]; int j = i-1;
            while (j >= 0 && tmp[j] > key) { tmp[j+1] = tmp[j]; j--; }
            tmp[j+1] = key;
        }
        for (int i = 0; i < 16; i++) TL[i] = (i < nk) ? tmp[i] : 3.4e38f;
    }
    __syncthreads();

    if (t < 17*8) {
        int seg = t >> 3, q = t & 7;
        float lo = (seg == 0)  ? -1e30f : TL[seg-1];
        float hi = (seg == 16) ?  1e30f : TL[seg];
        float smid;
        if (hi > 1e29f)       smid = lo + 1.f;
        else if (lo < -1e29f) smid = hi - 1.f;
        else                  smid = 0.5f*(lo + hi);
        float alpha = 0.f, beta = prmL[160+q];
        #pragma unroll
        for (int o = 0; o < 16; o++) {
            float a = prmL[o], c = prmL[16+o];
            if (a*smid + c > 0.f) {
                alpha += prmL[32+q*16+o]*a;
                beta  += prmL[32+q*16+o]*c;
            }
        }
        ws[OFF_TAB + seg*16 + q]     = alpha;
        ws[OFF_TAB + seg*16 + 8 + q] = beta;
    }
    if (t < 177) ws[OFF_PRM + t] = prmL[t];
    if (t < 16)  ws[OFF_T + t]   = TL[t];
}

// ---------------- transpose (+ setup in block 0) ----------------
__global__ __launch_bounds__(256) void transpose_setup_kernel(
    const float* __restrict__ fea, float* __restrict__ featT,
    const float* __restrict__ proj,
    const float* __restrict__ w0, const float* __restrict__ g0, const float* __restrict__ b0,
    const float* __restrict__ m0, const float* __restrict__ v0,
    const float* __restrict__ w1, const float* __restrict__ g1, const float* __restrict__ b1,
    const float* __restrict__ m1, const float* __restrict__ v1,
    const float* __restrict__ w2, const float* __restrict__ b2,
    float* __restrict__ ws) {
    __shared__ float prmL[177];
    __shared__ float TL[16];
    if (blockIdx.x == 0)
        setup_body(proj, w0, g0, b0, m0, v0, w1, g1, b1, m1, v1, w2, b2,
                   ws, threadIdx.x, prmL, TL);

    int t = blockIdx.x*256 + threadIdx.x;        // V*B*H*W
    int w = t % WW;
    int h = (t / WW) % HH;
    int b = (t / (WW*HH)) % BB;
    int v = t / (WW*HH*BB);
    const float* src = fea + (size_t)((v*BB + b)*CC) * HWp + h*WW + w;
    float* dst = featT + (size_t)((v*BB + b)*HWp + h*WW + w) * CC;
    #pragma unroll
    for (int c = 0; c < CC; c += 4) {
        float4 q;
        q.x = src[(c+0)*HWp];
        q.y = src[(c+1)*HWp];
        q.z = src[(c+2)*HWp];
        q.w = src[(c+3)*HWp];
        *reinterpret_cast<float4*>(dst + c) = q;
    }
}

__device__ __forceinline__ float half_max(float v) {
    v = fmaxf(v, __shfl_xor(v, 1));
    v = fmaxf(v, __shfl_xor(v, 2));
    v = fmaxf(v, __shfl_xor(v, 4));
    v = fmaxf(v, __shfl_xor(v, 8));
    v = fmaxf(v, __shfl_xor(v, 16));
    return v;
}

__device__ __forceinline__ float dot32(const float* __restrict__ col,
                                       const float* __restrict__ refp) {
    float acc = 0.f;
    #pragma unroll
    for (int c = 0; c < CC; c += 4) {
        float4 a = *reinterpret_cast<const float4*>(col + c);
        float4 r = *reinterpret_cast<const float4*>(refp + c);
        acc = fmaf(a.w, r.w, fmaf(a.z, r.z, fmaf(a.y, r.y, fmaf(a.x, r.x, acc))));
    }
    return acc;
}

// phase-B body (lane layout: d2 = lane&31): 17x16 seg-table MLP
__device__ __forceinline__ void mlp_out(
    float s0, float s1, float s2, float s3,
    int d2, int b, int p,
    const float* __restrict__ tabL, const float* __restrict__ Tg,
    const float* __restrict__ prm,
    float* __restrict__ out, float* __restrict__ simout) {
    float T0 = Tg[0], T1 = Tg[1], T2 = Tg[2], T3 = Tg[3];
    float T4 = Tg[4], T5 = Tg[5], T6 = Tg[6], T7 = Tg[7];
    float T8 = Tg[8], T9 = Tg[9], T10 = Tg[10], T11 = Tg[11];
    float T12 = Tg[12], T13 = Tg[13], T14 = Tg[14], T15 = Tg[15];
    float wq0 = prm[168], wq1 = prm[169], wq2 = prm[170], wq3 = prm[171];
    float wq4 = prm[172], wq5 = prm[173], wq6 = prm[174], wq7 = prm[175];
    float p176 = prm[176];

    float sv[NV] = {s0, s1, s2, s3};
    float vw[NV];
    #pragma unroll
    for (int v = 0; v < NV; v++) {
        float s = sv[v];
        int seg = 0;
        seg += (s > T0);  seg += (s > T1);  seg += (s > T2);  seg += (s > T3);
        seg += (s > T4);  seg += (s > T5);  seg += (s > T6);  seg += (s > T7);
        seg += (s > T8);  seg += (s > T9);  seg += (s > T10); seg += (s > T11);
        seg += (s > T12); seg += (s > T13); seg += (s > T14); seg += (s > T15);
        const float* row = &tabL[seg << 4];
        float4 A0 = *reinterpret_cast<const float4*>(row);
        float4 A1 = *reinterpret_cast<const float4*>(row + 4);
        float4 B0 = *reinterpret_cast<const float4*>(row + 8);
        float4 B1 = *reinterpret_cast<const float4*>(row + 12);
        float h2v = p176;
        h2v = fmaf(wq0, fmaxf(fmaf(A0.x, s, B0.x), 0.f), h2v);
        h2v = fmaf(wq1, fmaxf(fmaf(A0.y, s, B0.y), 0.f), h2v);
        h2v = fmaf(wq2, fmaxf(fmaf(A0.z, s, B0.z), 0.f), h2v);
        h2v = fmaf(wq3, fmaxf(fmaf(A0.w, s, B0.w), 0.f), h2v);
        h2v = fmaf(wq4, fmaxf(fmaf(A1.x, s, B1.x), 0.f), h2v);
        h2v = fmaf(wq5, fmaxf(fmaf(A1.y, s, B1.y), 0.f), h2v);
        h2v = fmaf(wq6, fmaxf(fmaf(A1.z, s, B1.z), 0.f), h2v);
        h2v = fmaf(wq7, fmaxf(fmaf(A1.w, s, B1.w), 0.f), h2v);
        float m = half_max(h2v);
        vw[v] = 1.f/(1.f + __expf(-m));
    }

    if (d2 == 0) out[OUT_VW + (b*NV + 0)*HWp + p] = vw[0];
    if (d2 == 1) out[OUT_VW + (b*NV + 1)*HWp + p] = vw[1];
    if (d2 == 2) out[OUT_VW + (b*NV + 2)*HWp + p] = vw[2];
    if (d2 == 3) out[OUT_VW + (b*NV + 3)*HWp + p] = vw[3];

    float wsum = 1e-5f + vw[0] + vw[1] + vw[2] + vw[3];
    float ssum = s0*vw[0] + s1*vw[1] + s2*vw[2] + s3*vw[3];
    simout[(b*DD + d2)*HWp + p] = ssum / wsum;
}

// general-path x-side tap pair
__device__ __forceinline__ float tap_blend(
    const float* __restrict__ vbv, int sub8, float sx,
    float ay0, float ay1, int r0, int r1,
    float4 rva, float4 rvb) {
    float x0f = floorf(sx);
    float wx1 = sx - x0f;
    float wx0 = 1.f - wx1;
    int xi0 = (int)x0f, xi1 = xi0 + 1;
    float ax0 = ((unsigned)xi0 < WW) ? wx0 : 0.f;
    float ax1 = ((unsigned)xi1 < WW) ? wx1 : 0.f;
    int xc0 = min(max(xi0, 0), WW-1);
    int xc1 = min(max(xi1, 0), WW-1);
    float w00 = ax0*ay0, w01 = ax1*ay0;
    const float* q00 = vbv + (((r0 + xc0) << 5) + sub8);
    const float* q01 = vbv + (((r0 + xc1) << 5) + sub8);
    float4 t00a = *reinterpret_cast<const float4*>(q00);
    float4 t00b = *reinterpret_cast<const float4*>(q00 + 4);
    float4 t01a = *reinterpret_cast<const float4*>(q01);
    float4 t01b = *reinterpret_cast<const float4*>(q01 + 4);

    float blx = fmaf(w01, t01a.x, w00*t00a.x);
    float bly = fmaf(w01, t01a.y, w00*t00a.y);
    float blz = fmaf(w01, t01a.z, w00*t00a.z);
    float blw = fmaf(w01, t01a.w, w00*t00a.w);
    float acc = fmaf(rva.w,blw, fmaf(rva.z,blz, fmaf(rva.y,bly, rva.x*blx)));
    blx = fmaf(w01, t01b.x, w00*t00b.x);
    bly = fmaf(w01, t01b.y, w00*t00b.y);
    blz = fmaf(w01, t01b.z, w00*t00b.z);
    blw = fmaf(w01, t01b.w, w00*t00b.w);
    acc = fmaf(rvb.w,blw, fmaf(rvb.z,blz, fmaf(rvb.y,bly, fmaf(rvb.x,blx, acc))));

    if (ay1 != 0.f) {
        float w10 = ax0*ay1, w11 = ax1*ay1;
        const float* q10 = vbv + (((r1 + xc0) << 5) + sub8);
        const float* q11 = vbv + (((r1 + xc1) << 5) + sub8);
        float4 t10a = *reinterpret_cast<const float4*>(q10);
        float4 t10b = *reinterpret_cast<const float4*>(q10 + 4);
        float4 t11a = *reinterpret_cast<const float4*>(q11);
        float4 t11b = *reinterpret_cast<const float4*>(q11 + 4);
        float cx = fmaf(w11, t11a.x, w10*t10a.x);
        float cy = fmaf(w11, t11a.y, w10*t10a.y);
        float cz = fmaf(w11, t11a.z, w10*t10a.z);
        float cw = fmaf(w11, t11a.w, w10*t10a.w);
        acc = fmaf(rva.w,cw, fmaf(rva.z,cz, fmaf(rva.y,cy, fmaf(rva.x,cx, acc))));
        cx = fmaf(w11, t11b.x, w10*t10b.x);
        cy = fmaf(w11, t11b.y, w10*t10b.y);
        cz = fmaf(w11, t11b.z, w10*t10b.z);
        cw = fmaf(w11, t11b.w, w10*t10b.w);
        acc = fmaf(rvb.w,cw, fmaf(rvb.z,cz, fmaf(rvb.y,cy, fmaf(rvb.x,cx, acc))));
    }
    return acc;
}

// ---------------- fused warp + sim + PWL-MLP + view aggregation ----------------
__global__ __launch_bounds__(256) void fused_sim_kernel(
    const float* __restrict__ featT, const float* __restrict__ rtAll,
    const float* __restrict__ prm, const float* __restrict__ Tg,
    const float* __restrict__ tabG, const float* __restrict__ flagG,
    const float* __restrict__ depthv,
    float* __restrict__ simout, float* __restrict__ out) {
    __shared__ __align__(16) float smemU[2720];   // union region (~10.9 KB)
    __shared__ __align__(16) float tabL[17*16];
    int* smemI = (int*)smemU;

    int t = threadIdx.x;
    int b = blockIdx.y;
    int pbase = blockIdx.x * PX;
    int hi  = pbase / WW;
    int wi0 = pbase % WW;
    float fy = (float)hi;

    bool fast = (flagG[b] != 0.f);   // block-uniform

    // ---- staging ----
    {
        int di = t >> 4, k = t & 15;
        float dep0 = depthv[(b*DD + di)*HWp + pbase + k];
        float dep1 = depthv[(b*DD + di + 16)*HWp + pbase + k];
        if (fast) {
            ZI(di, k)    = __builtin_amdgcn_rcpf(dep0);
            ZI(di+16, k) = __builtin_amdgcn_rcpf(dep1);
            if (t < 128) {      // ref features via float4: p = t>>3, c4 = (t&7)*4
                int p = t >> 3, c4 = (t & 7) * 4;
                float4 rq = *reinterpret_cast<const float4*>(
                    featT + (size_t)(b*HWp + pbase + p)*CC + c4);
                *reinterpret_cast<float4*>(&REF(p, c4)) = rq;
            }
        } else {
            DEP(di, k)    = dep0;
            DEP(di+16, k) = dep1;
        }
        tabL[t] = tabG[t];
        if (t < 16) tabL[256 + t] = tabG[256 + t];
        if (t == 0 && fast) BADF = 0;
    }
    __syncthreads();

    float rc[NV][12];
    #pragma unroll
    for (int v = 0; v < NV; v++)
        #pragma unroll
        for (int j = 0; j < 12; j++)
            rc[v][j] = rtAll[(b*NV + v)*12 + j];
    float bx0[NV], by0[NV], bz0[NV];
    #pragma unroll
    for (int v = 0; v < NV; v++) {
        bx0[v] = fmaf((float)wi0, rc[v][0], fmaf(fy, rc[v][1], rc[v][2]));
        by0[v] = fmaf((float)wi0, rc[v][3], fmaf(fy, rc[v][4], rc[v][5]));
        bz0[v] = fmaf((float)wi0, rc[v][6], fmaf(fy, rc[v][7], rc[v][8]));
    }

    bool needRestage = false;
    if (fast) {
        // ---- step 1: zi-range once per pixel-phase; per-view range analytic ----
        int p_loc = t >> 5, d = t & 31;
        for (int ph = 0; ph < 2; ph++) {
            int p = ph*8 + p_loc;
            float zi = ZI(d, p);
            float mnz = zi, mxz = zi;
            #pragma unroll
            for (int off = 1; off <= 16; off <<= 1) {
                mnz = fminf(mnz, __shfl_xor(mnz, off));
                mxz = fmaxf(mxz, __shfl_xor(mxz, off));
            }
            if (d == 0) {
                float fk = (float)p;
                #pragma unroll
                for (int v = 0; v < NV; v++) {
                    float bx = fmaf(fk, rc[v][0], bx0[v]);
                    float t0c = rc[v][9];
                    // sx = fmaf(t0c, zi, bx) is monotone in zi -> exact extremes
                    float sxa = fmaf(t0c, mnz, bx);
                    float sxb = fmaf(t0c, mxz, bx);
                    float mn = fminf(sxa, sxb), mx = fmaxf(sxa, sxb);
                    float by = fmaf(fk, rc[v][3], by0[v]);
                    float sy = by;
                    float sny = rintf(sy);
                    sy = (fabsf(sy - sny) < 1e-4f) ? sny : sy;
                    float y0f = floorf(sy);
                    float wy1 = sy - y0f, wy0 = 1.f - wy1;
                    int yi0 = (int)y0f, yi1 = yi0 + 1;
                    AY0(v, p) = ((unsigned)yi0 < HH) ? wy0 : 0.f;
                    AY1(v, p) = ((unsigned)yi1 < HH) ? wy1 : 0.f;
                    IR0(v, p) = min(max(yi0, 0), HH-1)*WW;
                    IR1(v, p) = min(max(yi1, 0), HH-1)*WW;
                    bool finite = (mn > -1e9f) && (mx < 1e9f) && (mn == mn) && (mx == mx);
                    int xb = finite ? (int)floorf(mn) : 0;
                    int slots = finite ? ((int)floorf(mx) - xb + 2) : MAXSLOT + 1;
                    IXB(v, p) = xb;
                    ISL(v, p) = slots;
                    if (slots > MAXSLOT) BADF = 1;
                }
            }
        }
        __syncthreads();
        if (BADF) { fast = false; needRestage = true; }
    }

    if (fast) {
        // ---- step 2: all-view dot tables, one pass ----
        {
            int v2 = t & 3, p2 = (t >> 2) & 15, i0 = t >> 6;   // i0: 0..3
            float ay0 = AY0(v2, p2), ay1 = AY1(v2, p2);
            int r0 = IR0(v2, p2), r1 = IR1(v2, p2);
            int xb = IXB(v2, p2), slots = ISL(v2, p2);
            const float* vbv = featT + (size_t)(((v2+1)*BB + b)*HWp)*CC;
            const float* refp = &REF(p2, 0);
            for (int i2 = i0; i2 < slots; i2 += 4) {
                int xc = min(max(xb + i2, 0), WW-1);
                float g = ay0 * dot32(vbv + ((r0 + xc) << 5), refp);
                if (ay1 != 0.f) g = fmaf(ay1, dot32(vbv + ((r1 + xc) << 5), refp), g);
                GT(v2, p2, i2) = g * (1.f/(float)CC);
            }
        }
        __syncthreads();
        // ---- step 3 fused with phase B ----
        {
            int p_loc = t >> 5, d = t & 31;
            for (int ph = 0; ph < 2; ph++) {
                int p = ph*8 + p_loc;
                float fk = (float)p;
                float zi = ZI(d, p);
                float sv[NV];
                #pragma unroll
                for (int v = 0; v < NV; v++) {
                    float bx = fmaf(fk, rc[v][0], bx0[v]);
                    float sx = fmaf(rc[v][9], zi, bx);
                    float x0f = floorf(sx);
                    float wx1 = sx - x0f, wx0 = 1.f - wx1;
                    int xi0 = (int)x0f, xi1 = xi0 + 1;
                    float ax0 = ((unsigned)xi0 < WW) ? wx0 : 0.f;
                    float ax1 = ((unsigned)xi1 < WW) ? wx1 : 0.f;
                    int ii = xi0 - IXB(v, p);
                    float g0 = GT(v, p, ii);
                    float g1 = GT(v, p, ii+1);
                    sv[v] = fmaf(ax0, g0, ax1*g1);
                }
                mlp_out(sv[0], sv[1], sv[2], sv[3], d, b, pbase + p,
                        tabL, Tg, prm, out, simout);
            }
        }
        return;
    }

    // ---------------- general path ----------------
    if (needRestage) {
        int di = t >> 4, k = t & 15;
        DEP(di, k)    = depthv[(b*DD + di)*HWp + pbase + k];
        DEP(di+16, k) = depthv[(b*DD + di + 16)*HWp + pbase + k];
        __syncthreads();
    }
    {
        int sub = t & 3;
        int dB  = (t >> 2) & 31;
        int kk  = t >> 7;
        int sub8 = sub*8;
        #pragma unroll 2
        for (int j = 0; j < PX/2; j++) {
            int kpix = j*2 + kk;
            int p = pbase + kpix;
            float fk = (float)kpix;
            float depth = DEP(dB, kpix);
            const float* refp = featT + (size_t)(b*HWp + p)*CC + sub8;
            float4 rva = *reinterpret_cast<const float4*>(refp);
            float4 rvb = *reinterpret_cast<const float4*>(refp + 4);

            #pragma unroll
            for (int v = 0; v < NV; v++) {
                float bx = fmaf(fk, rc[v][0], bx0[v]);
                float by = fmaf(fk, rc[v][3], by0[v]);
                float bz = fmaf(fk, rc[v][6], bz0[v]);
                float px = fmaf(bx, depth, rc[v][9]);
                float py = fmaf(by, depth, rc[v][10]);
                float pz = fmaf(bz, depth, rc[v][11]);
                float zi = __builtin_amdgcn_rcpf(pz);
                float sx = px * zi, sy = py * zi;
                float sny = rintf(sy);
                sy = (fabsf(sy - sny) < 1e-4f) ? sny : sy;
                float y0f = floorf(sy);
                float wy1 = sy - y0f, wy0 = 1.f - wy1;
                int yi0 = (int)y0f, yi1 = yi0 + 1;
                float ay0 = ((unsigned)yi0 < HH) ? wy0 : 0.f;
                float ay1 = ((unsigned)yi1 < HH) ? wy1 : 0.f;
                int yc0 = min(max(yi0, 0), HH-1);
                int yc1 = min(max(yi1, 0), HH-1);
                int r0 = yc0*WW, r1 = yc1*WW;
                const float* vbv = featT + (size_t)(((v+1)*BB + b)*HWp)*CC;
                float acc = tap_blend(vbv, sub8, sx, ay0, ay1, r0, r1, rva, rvb);
                acc += __shfl_xor(acc, 1);
                acc += __shfl_xor(acc, 2);
                if (sub == 0) SIMG(v, dB, kpix) = acc * (1.f/(float)CC);
            }
        }
        __syncthreads();

        int p8 = t >> 5;
        int d2 = t & 31;
        #pragma unroll
        for (int pi = 0; pi < PX/8; pi++) {
            int pidx = pi*8 + p8;
            mlp_out(SIMG(0, d2, pidx), SIMG(1, d2, pidx),
                    SIMG(2, d2, pidx), SIMG(3, d2, pidx),
                    d2, b, pbase + pidx, tabL, Tg, prm, out, simout);
        }
    }
}

// ---------------- fused 3x3x3 conv + softmax/argmax ----------------
__global__ __launch_bounds__(256) void convsm_kernel(
    const float* __restrict__ sim, const float* __restrict__ rw,
    const float* __restrict__ rb, const float* __restrict__ depthv,
    float* __restrict__ out) {
    __shared__ float tile[34*121 + 7];
    int t = threadIdx.x;
    int tw = blockIdx.x * 8;
    int th = blockIdx.y * 8;
    int b  = blockIdx.z;

    for (int i = t; i < 34*120; i += 256) {
        int e = i / 120; int rem = i % 120;
        int h = rem / 12, w = rem % 12;
        int gd = e - 1, gh = th + h - 1, gw = tw + w - 1;
        float v = 0.f;
        if (w < 10 && gd >= 0 && gd < DD && (unsigned)gh < HH && (unsigned)gw < WW)
            v = sim[((b*DD + gd)*HH + gh)*WW + gw];
        tile[e*121 + rem] = v;
    }
    __syncthreads();

    float wk[27];
    #pragma unroll
    for (int i = 0; i < 27; i++) wk[i] = rw[i];
    float bias = rb[0];

    int p  = t >> 2, dq = t & 3;
    int ph = p >> 3, pw = p & 7;
    int d0 = dq * 8;

    float cost[8];
    #pragma unroll
    for (int j = 0; j < 8; j++) cost[j] = bias;
    #pragma unroll
    for (int e = 0; e < 10; e++) {
        int el = d0 + e;
        float s0 = 0.f, s1 = 0.f, s2 = 0.f;
        #pragma unroll
        for (int kh = 0; kh < 3; kh++) {
            #pragma unroll
            for (int kw = 0; kw < 3; kw++) {
                float x = tile[el*121 + (ph+kh)*12 + (pw+kw)];
                s0 = fmaf(wk[0*9 + kh*3 + kw], x, s0);
                s1 = fmaf(wk[1*9 + kh*3 + kw], x, s1);
                s2 = fmaf(wk[2*9 + kh*3 + kw], x, s2);
            }
        }
        if (e < 8)            cost[e]   += s0;
        if (e >= 1 && e <= 8) cost[e-1] += s1;
        if (e >= 2)           cost[e-2] += s2;
    }

    int pg = (th + ph)*WW + (tw + pw);
    #pragma unroll
    for (int j = 0; j < 8; j++)
        out[OUT_COST + (b*DD + d0 + j)*HWp + pg] = cost[j];

    float m = cost[0]; int mi = d0;
    #pragma unroll
    for (int j = 1; j < 8; j++) { if (cost[j] > m) { m = cost[j]; mi = d0 + j; } }
    #pragma unroll
    for (int off = 1; off <= 2; off <<= 1) {
        float m2 = __shfl_xor(m, off);
        int  i2 = __shfl_xor(mi, off);
        if (m2 > m || (m2 == m && i2 < mi)) { m = m2; mi = i2; }
    }
    float sum = 0.f;
    float e8[8];
    #pragma unroll
    for (int j = 0; j < 8; j++) { e8[j] = __expf(cost[j] - m); sum += e8[j]; }
    #pragma unroll
    for (int off = 1; off <= 2; off <<= 1) sum += __shfl_xor(sum, off);
    float inv = 1.f / sum;
    #pragma unroll
    for (int j = 0; j < 8; j++)
        out[OUT_PROB + (b*DD + d0 + j)*HWp + pg] = e8[j] * inv;
    if (dq == 0) {
        out[OUT_DEPTH + b*HWp + pg] = depthv[(b*DD + mi)*HWp + pg];
        out[OUT_CONF  + b*HWp + pg] = inv;
    }
}

extern "C" void kernel_launch(void* const* d_in, const int* in_sizes, int n_in,
                              void* d_out, int out_size, void* d_ws, size_t ws_size,
                              hipStream_t stream) {
    const float* features = (const float*)d_in[0];
    const float* proj     = (const float*)d_in[1];
    const float* depthv   = (const float*)d_in[2];
    const float* w0 = (const float*)d_in[4];
    const float* g0 = (const float*)d_in[5];
    const float* b0 = (const float*)d_in[6];
    const float* m0 = (const float*)d_in[7];
    const float* v0 = (const float*)d_in[8];
    const float* w1 = (const float*)d_in[9];
    const float* g1 = (const float*)d_in[10];
    const float* b1 = (const float*)d_in[11];
    const float* m1 = (const float*)d_in[12];
    const float* v1 = (const float*)d_in[13];
    const float* w2 = (const float*)d_in[14];
    const float* b2 = (const float*)d_in[15];
    const float* rw = (const float*)d_in[16];
    const float* rb = (const float*)d_in[17];
    float* out = (float*)d_out;
    float* ws  = (float*)d_ws;

    transpose_setup_kernel<<<VV*BB*HWp/256, 256, 0, stream>>>(
        features, ws + OFF_FEAT, proj,
        w0, g0, b0, m0, v0, w1, g1, b1, m1, v1, w2, b2, ws);

    fused_sim_kernel<<<dim3(HWp/PX, BB), 256, 0, stream>>>(
        ws + OFF_FEAT, ws + OFF_RT, ws + OFF_PRM, ws + OFF_T, ws + OFF_TAB,
        ws + OFF_FLAG, depthv, ws + OFF_SIM, out);

    convsm_kernel<<<dim3(WW/8, HH/8, BB), 256, 0, stream>>>(
        ws + OFF_SIM, rw, rb, depthv, out);
}

// Round 20
// 76.813 us; speedup vs baseline: 1.1416x; 1.0094x over previous
//
#include <hip/hip_runtime.h>
#include <math.h>

#define BB 2
#define VV 5
#define CC 32
#define HH 128
#define WW 160
#define DD 32
#define HWp (HH*WW)          // 20480
#define NV (VV-1)            // 4 src views
#define PX 16                // pixels per block (divides WW)
#define MAXSLOT 18           // max x-table entries per (pixel,view)
#define UWMAX 44             // max union-column width per view

// ---- workspace float offsets ----
#define OFF_RT   0                                   // B*NV*12 = 96
#define OFF_PRM  96                                  // 177 net params
#define OFF_FEAT 512                                 // f32 features V*B*HW*C
#define OFF_SIM  (OFF_FEAT + VV*BB*HWp*CC)           // B*D*HW similarity
#define OFF_T    (OFF_SIM + BB*DD*HWp)               // 16 sorted kinks
#define OFF_TAB  (OFF_T + 16)                        // 17*16 segment table
#define OFF_FLAG (OFF_TAB + 17*16)                   // BB fast-geometry flags

// ---- output float offsets ----
#define OUT_DEPTH 0
#define OUT_CONF  (BB*HWp)
#define OUT_PROB  (2*BB*HWp)
#define OUT_COST  (OUT_PROB + BB*DD*HWp)
#define OUT_VW    (OUT_COST + BB*DD*HWp)

// ---- fused_sim LDS union layout (floats into smemU[8544]) ----
#define ZI(d,k)     smemU[(d)*17 + (k)]
#define DEP(d,k)    smemU[(d)*17 + (k)]
#define REF(p,c)    smemU[544 + (p)*36 + (c)]
#define GT(v,p,i)   smemU[1120 + ((v)*16 + (p))*18 + (i)]
#define AY0(v,p)    smemU[2272 + (v)*16 + (p)]
#define AY1(v,p)    smemU[2336 + (v)*16 + (p)]
#define IR0(v,p)    smemI[2400 + (v)*16 + (p)]
#define IR1(v,p)    smemI[2464 + (v)*16 + (p)]
#define IXB(v,p)    smemI[2528 + (v)*16 + (p)]
#define ISL(v,p)    smemI[2592 + (v)*16 + (p)]
#define BADF        smemI[2656]
#define SIMG(v,d,p) smemU[544 + (((v)*32 + (d))*17 + (p))]
// union-column staging (fast+uniRow path only): padded stride 33
#define COLU(v,ux,c) smemU[2720 + (v)*(UWMAX*33) + (ux)*33 + (c)]
#define UOKI(v)     smemI[8528 + (v)]
#define UXLOI(v)    smemI[8532 + (v)]
#define UWI(v)      smemI[8536 + (v)]

// ---------------- setup body (runs in block 0 of transpose kernel) ----------
__device__ void build_proj(const float* proj, int b, int v, double M[4][4]) {
    const float* E = proj + (((b*VV + v)*2 + 0)*16);
    const float* K = proj + (((b*VV + v)*2 + 1)*16);
    for (int r = 0; r < 3; r++)
        for (int c = 0; c < 4; c++) {
            double s = 0.0;
            for (int k = 0; k < 3; k++) s += (double)K[r*4+k] * (double)E[k*4+c];
            M[r][c] = s;
        }
    for (int c = 0; c < 4; c++) M[3][c] = (double)E[12+c];
}

__device__ void inv4(const double M[4][4], double out[4][4]) {
    double a[4][8];
    for (int i = 0; i < 4; i++)
        for (int j = 0; j < 4; j++) { a[i][j] = M[i][j]; a[i][4+j] = (i == j) ? 1.0 : 0.0; }
    for (int col = 0; col < 4; col++) {
        int piv = col; double best = fabs(a[col][col]);
        for (int r = col+1; r < 4; r++) if (fabs(a[r][col]) > best) { best = fabs(a[r][col]); piv = r; }
        if (piv != col) for (int j = 0; j < 8; j++) { double t = a[col][j]; a[col][j] = a[piv][j]; a[piv][j] = t; }
        double dinv = 1.0 / a[col][col];
        for (int j = 0; j < 8; j++) a[col][j] *= dinv;
        for (int r = 0; r < 4; r++) {
            if (r == col) continue;
            double f = a[r][col];
            for (int j = 0; j < 8; j++) a[r][j] -= f * a[col][j];
        }
    }
    for (int i = 0; i < 4; i++) for (int j = 0; j < 4; j++) out[i][j] = a[i][4+j];
}

__device__ void setup_body(const float* __restrict__ proj,
    const float* __restrict__ w0, const float* __restrict__ g0, const float* __restrict__ b0,
    const float* __restrict__ m0, const float* __restrict__ v0,
    const float* __restrict__ w1, const float* __restrict__ g1, const float* __restrict__ b1,
    const float* __restrict__ m1, const float* __restrict__ v1,
    const float* __restrict__ w2, const float* __restrict__ b2,
    float* __restrict__ ws, int t,
    float* __restrict__ prmL, float* __restrict__ TL) {

    if (t < BB*NV) {
        int b = t / NV, v = 1 + (t % NV);
        double refM[4][4], inv[4][4], S[4][4];
        build_proj(proj, b, 0, refM);
        inv4(refM, inv);
        build_proj(proj, b, v, S);
        float* rt = ws + OFF_RT + (b*NV + (v-1))*12;
        for (int r = 0; r < 3; r++) {
            for (int c = 0; c < 3; c++) {
                double s = 0.0;
                for (int k = 0; k < 4; k++) s += S[r][k] * inv[k][c];
                rt[r*3 + c] = (float)s;
            }
            double s = 0.0;
            for (int k = 0; k < 4; k++) s += S[r][k] * inv[k][3];
            rt[9 + r] = (float)s;
        }
    }

    if (t < 16) {
        float sc = g0[t] / sqrtf(v0[t] + 1e-5f);
        prmL[t]      = w0[t] * sc;
        prmL[16 + t] = b0[t] - m0[t] * sc;
    }
    if (t >= 32 && t < 160) {
        int i = t - 32, q = i >> 4, o = i & 15;
        float sc = g1[q] / sqrtf(v1[q] + 1e-5f);
        prmL[32 + q*16 + o] = w1[q*16 + o] * sc;
    }
    if (t >= 160 && t < 168) {
        int q = t - 160;
        float sc = g1[q] / sqrtf(v1[q] + 1e-5f);
        prmL[160 + q] = b1[q] - m1[q] * sc;
        prmL[168 + q] = w2[q];
    }
    if (t == 176) prmL[176] = b2[0];
    __syncthreads();

    // fast-geometry detection (pz = depth, sy depth-independent)
    if (t < BB) {
        int ok = 1;
        for (int i = 0; i < NV; i++) {
            const float* ri = ws + OFF_RT + (t*NV + i)*12;
            ok &= (fabsf(ri[6])        < 1e-6f);
            ok &= (fabsf(ri[7])        < 1e-6f);
            ok &= (fabsf(ri[8] - 1.f)  < 1e-6f);
            ok &= (fabsf(ri[10])       < 1e-6f);
            ok &= (fabsf(ri[11])       < 1e-6f);
        }
        ws[OFF_FLAG + t] = ok ? 1.f : 0.f;
    }

    if (t == 0) {
        float tmp[16]; int nk = 0;
        for (int o = 0; o < 16; o++) {
            float a = prmL[o];
            if (a != 0.f) tmp[nk++] = -prmL[16+o] / a;
        }
        for (int i = 1; i < nk; i++) {
            float key = tmp[i]; int j = i-1;
            while (j >= 0 && tmp[j] > key) { tmp[j+1] = tmp[j]; j--; }
            tmp[j+1] = key;
        }
        for (int i = 0; i < 16; i++) TL[i] = (i < nk) ? tmp[i] : 3.4e38f;
    }
    __syncthreads();

    if (t < 17*8) {
        int seg = t >> 3, q = t & 7;
        float lo = (seg == 0)  ? -1e30f : TL[seg-1];
        float hi = (seg == 16) ?  1e30f : TL[seg];
        float smid;
        if (hi > 1e29f)       smid = lo + 1.f;
        else if (lo < -1e29f) smid = hi - 1.f;
        else                  smid = 0.5f*(lo + hi);
        float alpha = 0.f, beta = prmL[160+q];
        #pragma unroll
        for (int o = 0; o < 16; o++) {
            float a = prmL[o], c = prmL[16+o];
            if (a*smid + c > 0.f) {
                alpha += prmL[32+q*16+o]*a;
                beta  += prmL[32+q*16+o]*c;
            }
        }
        ws[OFF_TAB + seg*16 + q]     = alpha;
        ws[OFF_TAB + seg*16 + 8 + q] = beta;
    }
    if (t < 177) ws[OFF_PRM + t] = prmL[t];
    if (t < 16)  ws[OFF_T + t]   = TL[t];
}

// ---------------- transpose (+ setup in block 0) ----------------
__global__ __launch_bounds__(256) void transpose_setup_kernel(
    const float* __restrict__ fea, float* __restrict__ featT,
    const float* __restrict__ proj,
    const float* __restrict__ w0, const float* __restrict__ g0, const float* __restrict__ b0,
    const float* __restrict__ m0, const float* __restrict__ v0,
    const float* __restrict__ w1, const float* __restrict__ g1, const float* __restrict__ b1,
    const float* __restrict__ m1, const float* __restrict__ v1,
    const float* __restrict__ w2, const float* __restrict__ b2,
    float* __restrict__ ws) {
    __shared__ float prmL[177];
    __shared__ float TL[16];
    if (blockIdx.x == 0)
        setup_body(proj, w0, g0, b0, m0, v0, w1, g1, b1, m1, v1, w2, b2,
                   ws, threadIdx.x, prmL, TL);

    int t = blockIdx.x*256 + threadIdx.x;        // V*B*H*W
    int w = t % WW;
    int h = (t / WW) % HH;
    int b = (t / (WW*HH)) % BB;
    int v = t / (WW*HH*BB);
    const float* src = fea + (size_t)((v*BB + b)*CC) * HWp + h*WW + w;
    float* dst = featT + (size_t)((v*BB + b)*HWp + h*WW + w) * CC;
    #pragma unroll
    for (int c = 0; c < CC; c += 4) {
        float4 q;
        q.x = src[(c+0)*HWp];
        q.y = src[(c+1)*HWp];
        q.z = src[(c+2)*HWp];
        q.w = src[(c+3)*HWp];
        *reinterpret_cast<float4*>(dst + c) = q;
    }
}

__device__ __forceinline__ float half_max(float v) {
    v = fmaxf(v, __shfl_xor(v, 1));
    v = fmaxf(v, __shfl_xor(v, 2));
    v = fmaxf(v, __shfl_xor(v, 4));
    v = fmaxf(v, __shfl_xor(v, 8));
    v = fmaxf(v, __shfl_xor(v, 16));
    return v;
}

__device__ __forceinline__ float dot32(const float* __restrict__ col,
                                       const float* __restrict__ refp) {
    float acc = 0.f;
    #pragma unroll
    for (int c = 0; c < CC; c += 4) {
        float4 a = *reinterpret_cast<const float4*>(col + c);
        float4 r = *reinterpret_cast<const float4*>(refp + c);
        acc = fmaf(a.w, r.w, fmaf(a.z, r.z, fmaf(a.y, r.y, fmaf(a.x, r.x, acc))));
    }
    return acc;
}

// LDS-source dot with identical FMA nesting order (bitwise same result)
__device__ __forceinline__ float dot32_lds(const float* __restrict__ col,
                                           const float* __restrict__ refp) {
    float acc = 0.f;
    #pragma unroll
    for (int c = 0; c < CC; c += 4) {
        acc = fmaf(col[c+3], refp[c+3],
              fmaf(col[c+2], refp[c+2],
              fmaf(col[c+1], refp[c+1],
              fmaf(col[c+0], refp[c+0], acc))));
    }
    return acc;
}

// phase-B body (lane layout: d2 = lane&31): 17x16 seg-table MLP
__device__ __forceinline__ void mlp_out(
    float s0, float s1, float s2, float s3,
    int d2, int b, int p,
    const float* __restrict__ tabL, const float* __restrict__ Tg,
    const float* __restrict__ prm,
    float* __restrict__ out, float* __restrict__ simout) {
    float T0 = Tg[0], T1 = Tg[1], T2 = Tg[2], T3 = Tg[3];
    float T4 = Tg[4], T5 = Tg[5], T6 = Tg[6], T7 = Tg[7];
    float T8 = Tg[8], T9 = Tg[9], T10 = Tg[10], T11 = Tg[11];
    float T12 = Tg[12], T13 = Tg[13], T14 = Tg[14], T15 = Tg[15];
    float wq0 = prm[168], wq1 = prm[169], wq2 = prm[170], wq3 = prm[171];
    float wq4 = prm[172], wq5 = prm[173], wq6 = prm[174], wq7 = prm[175];
    float p176 = prm[176];

    float sv[NV] = {s0, s1, s2, s3};
    float vw[NV];
    #pragma unroll
    for (int v = 0; v < NV; v++) {
        float s = sv[v];
        int seg = 0;
        seg += (s > T0);  seg += (s > T1);  seg += (s > T2);  seg += (s > T3);
        seg += (s > T4);  seg += (s > T5);  seg += (s > T6);  seg += (s > T7);
        seg += (s > T8);  seg += (s > T9);  seg += (s > T10); seg += (s > T11);
        seg += (s > T12); seg += (s > T13); seg += (s > T14); seg += (s > T15);
        const float* row = &tabL[seg << 4];
        float4 A0 = *reinterpret_cast<const float4*>(row);
        float4 A1 = *reinterpret_cast<const float4*>(row + 4);
        float4 B0 = *reinterpret_cast<const float4*>(row + 8);
        float4 B1 = *reinterpret_cast<const float4*>(row + 12);
        float h2v = p176;
        h2v = fmaf(wq0, fmaxf(fmaf(A0.x, s, B0.x), 0.f), h2v);
        h2v = fmaf(wq1, fmaxf(fmaf(A0.y, s, B0.y), 0.f), h2v);
        h2v = fmaf(wq2, fmaxf(fmaf(A0.z, s, B0.z), 0.f), h2v);
        h2v = fmaf(wq3, fmaxf(fmaf(A0.w, s, B0.w), 0.f), h2v);
        h2v = fmaf(wq4, fmaxf(fmaf(A1.x, s, B1.x), 0.f), h2v);
        h2v = fmaf(wq5, fmaxf(fmaf(A1.y, s, B1.y), 0.f), h2v);
        h2v = fmaf(wq6, fmaxf(fmaf(A1.z, s, B1.z), 0.f), h2v);
        h2v = fmaf(wq7, fmaxf(fmaf(A1.w, s, B1.w), 0.f), h2v);
        float m = half_max(h2v);
        vw[v] = 1.f/(1.f + __expf(-m));
    }

    if (d2 == 0) out[OUT_VW + (b*NV + 0)*HWp + p] = vw[0];
    if (d2 == 1) out[OUT_VW + (b*NV + 1)*HWp + p] = vw[1];
    if (d2 == 2) out[OUT_VW + (b*NV + 2)*HWp + p] = vw[2];
    if (d2 == 3) out[OUT_VW + (b*NV + 3)*HWp + p] = vw[3];

    float wsum = 1e-5f + vw[0] + vw[1] + vw[2] + vw[3];
    float ssum = s0*vw[0] + s1*vw[1] + s2*vw[2] + s3*vw[3];
    simout[(b*DD + d2)*HWp + p] = ssum / wsum;
}

// general-path x-side tap pair
__device__ __forceinline__ float tap_blend(
    const float* __restrict__ vbv, int sub8, float sx,
    float ay0, float ay1, int r0, int r1,
    float4 rva, float4 rvb) {
    float x0f = floorf(sx);
    float wx1 = sx - x0f;
    float wx0 = 1.f - wx1;
    int xi0 = (int)x0f, xi1 = xi0 + 1;
    float ax0 = ((unsigned)xi0 < WW) ? wx0 : 0.f;
    float ax1 = ((unsigned)xi1 < WW) ? wx1 : 0.f;
    int xc0 = min(max(xi0, 0), WW-1);
    int xc1 = min(max(xi1, 0), WW-1);
    float w00 = ax0*ay0, w01 = ax1*ay0;
    const float* q00 = vbv + (((r0 + xc0) << 5) + sub8);
    const float* q01 = vbv + (((r0 + xc1) << 5) + sub8);
    float4 t00a = *reinterpret_cast<const float4*>(q00);
    float4 t00b = *reinterpret_cast<const float4*>(q00 + 4);
    float4 t01a = *reinterpret_cast<const float4*>(q01);
    float4 t01b = *reinterpret_cast<const float4*>(q01 + 4);

    float blx = fmaf(w01, t01a.x, w00*t00a.x);
    float bly = fmaf(w01, t01a.y, w00*t00a.y);
    float blz = fmaf(w01, t01a.z, w00*t00a.z);
    float blw = fmaf(w01, t01a.w, w00*t00a.w);
    float acc = fmaf(rva.w,blw, fmaf(rva.z,blz, fmaf(rva.y,bly, rva.x*blx)));
    blx = fmaf(w01, t01b.x, w00*t00b.x);
    bly = fmaf(w01, t01b.y, w00*t00b.y);
    blz = fmaf(w01, t01b.z, w00*t00b.z);
    blw = fmaf(w01, t01b.w, w00*t00b.w);
    acc = fmaf(rvb.w,blw, fmaf(rvb.z,blz, fmaf(rvb.y,bly, fmaf(rvb.x,blx, acc))));

    if (ay1 != 0.f) {
        float w10 = ax0*ay1, w11 = ax1*ay1;
        const float* q10 = vbv + (((r1 + xc0) << 5) + sub8);
        const float* q11 = vbv + (((r1 + xc1) << 5) + sub8);
        float4 t10a = *reinterpret_cast<const float4*>(q10);
        float4 t10b = *reinterpret_cast<const float4*>(q10 + 4);
        float4 t11a = *reinterpret_cast<const float4*>(q11);
        float4 t11b = *reinterpret_cast<const float4*>(q11 + 4);
        float cx = fmaf(w11, t11a.x, w10*t10a.x);
        float cy = fmaf(w11, t11a.y, w10*t10a.y);
        float cz = fmaf(w11, t11a.z, w10*t10a.z);
        float cw = fmaf(w11, t11a.w, w10*t10a.w);
        acc = fmaf(rva.w,cw, fmaf(rva.z,cz, fmaf(rva.y,cy, fmaf(rva.x,cx, acc))));
        cx = fmaf(w11, t11b.x, w10*t10b.x);
        cy = fmaf(w11, t11b.y, w10*t10b.y);
        cz = fmaf(w11, t11b.z, w10*t10b.z);
        cw = fmaf(w11, t11b.w, w10*t10b.w);
        acc = fmaf(rvb.w,cw, fmaf(rvb.z,cz, fmaf(rvb.y,cy, fmaf(rvb.x,cx, acc))));
    }
    return acc;
}

// ---------------- fused warp + sim + PWL-MLP + view aggregation ----------------
__global__ __launch_bounds__(256) void fused_sim_kernel(
    const float* __restrict__ featT, const float* __restrict__ rtAll,
    const float* __restrict__ prm, const float* __restrict__ Tg,
    const float* __restrict__ tabG, const float* __restrict__ flagG,
    const float* __restrict__ depthv,
    float* __restrict__ simout, float* __restrict__ out) {
    __shared__ __align__(16) float smemU[8544];   // union region (~34 KB)
    __shared__ __align__(16) float tabL[17*16];
    int* smemI = (int*)smemU;

    int t = threadIdx.x;
    int b = blockIdx.y;
    int pbase = blockIdx.x * PX;
    int hi  = pbase / WW;
    int wi0 = pbase % WW;
    float fy = (float)hi;

    bool fast = (flagG[b] != 0.f);   // block-uniform

    // ---- staging ----
    {
        int di = t >> 4, k = t & 15;
        float dep0 = depthv[(b*DD + di)*HWp + pbase + k];
        float dep1 = depthv[(b*DD + di + 16)*HWp + pbase + k];
        if (fast) {
            ZI(di, k)    = __builtin_amdgcn_rcpf(dep0);
            ZI(di+16, k) = __builtin_amdgcn_rcpf(dep1);
            if (t < 128) {      // ref features via float4: p = t>>3, c4 = (t&7)*4
                int p = t >> 3, c4 = (t & 7) * 4;
                float4 rq = *reinterpret_cast<const float4*>(
                    featT + (size_t)(b*HWp + pbase + p)*CC + c4);
                *reinterpret_cast<float4*>(&REF(p, c4)) = rq;
            }
        } else {
            DEP(di, k)    = dep0;
            DEP(di+16, k) = dep1;
        }
        tabL[t] = tabG[t];
        if (t < 16) tabL[256 + t] = tabG[256 + t];
        if (t == 0 && fast) BADF = 0;
    }
    __syncthreads();

    float rc[NV][12];
    #pragma unroll
    for (int v = 0; v < NV; v++)
        #pragma unroll
        for (int j = 0; j < 12; j++)
            rc[v][j] = rtAll[(b*NV + v)*12 + j];
    float bx0[NV], by0[NV], bz0[NV];
    #pragma unroll
    for (int v = 0; v < NV; v++) {
        bx0[v] = fmaf((float)wi0, rc[v][0], fmaf(fy, rc[v][1], rc[v][2]));
        by0[v] = fmaf((float)wi0, rc[v][3], fmaf(fy, rc[v][4], rc[v][5]));
        bz0[v] = fmaf((float)wi0, rc[v][6], fmaf(fy, rc[v][7], rc[v][8]));
    }

    bool needRestage = false;
    if (fast) {
        // ---- step 1: zi-range once per pixel-phase; per-view range analytic ----
        int p_loc = t >> 5, d = t & 31;
        for (int ph = 0; ph < 2; ph++) {
            int p = ph*8 + p_loc;
            float zi = ZI(d, p);
            float mnz = zi, mxz = zi;
            #pragma unroll
            for (int off = 1; off <= 16; off <<= 1) {
                mnz = fminf(mnz, __shfl_xor(mnz, off));
                mxz = fmaxf(mxz, __shfl_xor(mxz, off));
            }
            if (d == 0) {
                float fk = (float)p;
                #pragma unroll
                for (int v = 0; v < NV; v++) {
                    float bx = fmaf(fk, rc[v][0], bx0[v]);
                    float t0c = rc[v][9];
                    float sxa = fmaf(t0c, mnz, bx);
                    float sxb = fmaf(t0c, mxz, bx);
                    float mn = fminf(sxa, sxb), mx = fmaxf(sxa, sxb);
                    float by = fmaf(fk, rc[v][3], by0[v]);
                    float sy = by;
                    float sny = rintf(sy);
                    sy = (fabsf(sy - sny) < 1e-4f) ? sny : sy;
                    float y0f = floorf(sy);
                    float wy1 = sy - y0f, wy0 = 1.f - wy1;
                    int yi0 = (int)y0f, yi1 = yi0 + 1;
                    AY0(v, p) = ((unsigned)yi0 < HH) ? wy0 : 0.f;
                    AY1(v, p) = ((unsigned)yi1 < HH) ? wy1 : 0.f;
                    IR0(v, p) = min(max(yi0, 0), HH-1)*WW;
                    IR1(v, p) = min(max(yi1, 0), HH-1)*WW;
                    bool finite = (mn > -1e9f) && (mx < 1e9f) && (mn == mn) && (mx == mx);
                    int xb = finite ? (int)floorf(mn) : 0;
                    int slots = finite ? ((int)floorf(mx) - xb + 2) : MAXSLOT + 1;
                    IXB(v, p) = xb;
                    ISL(v, p) = slots;
                    if (slots > MAXSLOT) BADF = 1;
                }
            }
        }
        __syncthreads();
        if (BADF) { fast = false; needRestage = true; }
    }

    bool uni = false;
    if (fast) {
        // ---- step 1.5: uniform-row + union-range detection (wave 0) ----
        if (t < 64) {
            int v = t >> 4, p = t & 15;
            int ok = (AY1(v, p) == 0.f) && (IR0(v, p) == IR0(v, 0)) ? 1 : 0;
            int xlo = IXB(v, p);
            int xhi = xlo + ISL(v, p) - 1;
            #pragma unroll
            for (int off = 1; off <= 8; off <<= 1) {
                ok  &= __shfl_xor(ok, off);
                xlo  = min(xlo, __shfl_xor(xlo, off));
                xhi  = max(xhi, __shfl_xor(xhi, off));
            }
            if (p == 0) {
                int wdt = xhi - xlo + 1;
                UOKI(v)  = (ok && wdt <= UWMAX) ? 1 : 0;
                UXLOI(v) = xlo;
                UWI(v)   = wdt;
            }
        }
        __syncthreads();
        uni = UOKI(0) && UOKI(1) && UOKI(2) && UOKI(3);
    }

    if (fast) {
        if (uni) {
            // ---- step 2a: coalesced union-column staging, all views ----
            for (int i = t; i < NV*UWMAX*8; i += 256) {
                int v  = i / (UWMAX*8);
                int rem = i - v*(UWMAX*8);
                int ux = rem >> 3, c4 = (rem & 7) * 4;
                if (ux < UWI(v)) {
                    int xc = min(max(UXLOI(v) + ux, 0), WW-1);
                    int r0 = IR0(v, 0);
                    const float* src = featT + (size_t)(((v+1)*BB + b)*HWp)*CC
                                       + ((r0 + xc) << 5) + c4;
                    float4 q = *reinterpret_cast<const float4*>(src);
                    COLU(v, ux, c4+0) = q.x;
                    COLU(v, ux, c4+1) = q.y;
                    COLU(v, ux, c4+2) = q.z;
                    COLU(v, ux, c4+3) = q.w;
                }
            }
            __syncthreads();
            // ---- step 2b: dot tables from LDS (ay1 == 0 in uni mode) ----
            {
                int v2 = t & 3, p2 = (t >> 2) & 15, i0 = t >> 6;
                float ay0 = AY0(v2, p2);
                int xb = IXB(v2, p2), slots = ISL(v2, p2);
                int xoff = xb - UXLOI(v2);
                const float* refp = &REF(p2, 0);
                for (int i2 = i0; i2 < slots; i2 += 4) {
                    const float* col = &COLU(v2, xoff + i2, 0);
                    float g = ay0 * dot32_lds(col, refp);
                    GT(v2, p2, i2) = g * (1.f/(float)CC);
                }
            }
            __syncthreads();
        } else {
            // ---- step 2 (global fallback): all-view dot tables ----
            {
                int v2 = t & 3, p2 = (t >> 2) & 15, i0 = t >> 6;
                float ay0 = AY0(v2, p2), ay1 = AY1(v2, p2);
                int r0 = IR0(v2, p2), r1 = IR1(v2, p2);
                int xb = IXB(v2, p2), slots = ISL(v2, p2);
                const float* vbv = featT + (size_t)(((v2+1)*BB + b)*HWp)*CC;
                const float* refp = &REF(p2, 0);
                for (int i2 = i0; i2 < slots; i2 += 4) {
                    int xc = min(max(xb + i2, 0), WW-1);
                    float g = ay0 * dot32(vbv + ((r0 + xc) << 5), refp);
                    if (ay1 != 0.f) g = fmaf(ay1, dot32(vbv + ((r1 + xc) << 5), refp), g);
                    GT(v2, p2, i2) = g * (1.f/(float)CC);
                }
            }
            __syncthreads();
        }
        // ---- step 3 fused with phase B ----
        {
            int p_loc = t >> 5, d = t & 31;
            for (int ph = 0; ph < 2; ph++) {
                int p = ph*8 + p_loc;
                float fk = (float)p;
                float zi = ZI(d, p);
                float sv[NV];
                #pragma unroll
                for (int v = 0; v < NV; v++) {
                    float bx = fmaf(fk, rc[v][0], bx0[v]);
                    float sx = fmaf(rc[v][9], zi, bx);
                    float x0f = floorf(sx);
                    float wx1 = sx - x0f, wx0 = 1.f - wx1;
                    int xi0 = (int)x0f, xi1 = xi0 + 1;
                    float ax0 = ((unsigned)xi0 < WW) ? wx0 : 0.f;
                    float ax1 = ((unsigned)xi1 < WW) ? wx1 : 0.f;
                    int ii = xi0 - IXB(v, p);
                    float g0 = GT(v, p, ii);
                    float g1 = GT(v, p, ii+1);
                    sv[v] = fmaf(ax0, g0, ax1*g1);
                }
                mlp_out(sv[0], sv[1], sv[2], sv[3], d, b, pbase + p,
                        tabL, Tg, prm, out, simout);
            }
        }
        return;
    }

    // ---------------- general path ----------------
    if (needRestage) {
        int di = t >> 4, k = t & 15;
        DEP(di, k)    = depthv[(b*DD + di)*HWp + pbase + k];
        DEP(di+16, k) = depthv[(b*DD + di + 16)*HWp + pbase + k];
        __syncthreads();
    }
    {
        int sub = t & 3;
        int dB  = (t >> 2) & 31;
        int kk  = t >> 7;
        int sub8 = sub*8;
        #pragma unroll 2
        for (int j = 0; j < PX/2; j++) {
            int kpix = j*2 + kk;
            int p = pbase + kpix;
            float fk = (float)kpix;
            float depth = DEP(dB, kpix);
            const float* refp = featT + (size_t)(b*HWp + p)*CC + sub8;
            float4 rva = *reinterpret_cast<const float4*>(refp);
            float4 rvb = *reinterpret_cast<const float4*>(refp + 4);

            #pragma unroll
            for (int v = 0; v < NV; v++) {
                float bx = fmaf(fk, rc[v][0], bx0[v]);
                float by = fmaf(fk, rc[v][3], by0[v]);
                float bz = fmaf(fk, rc[v][6], bz0[v]);
                float px = fmaf(bx, depth, rc[v][9]);
                float py = fmaf(by, depth, rc[v][10]);
                float pz = fmaf(bz, depth, rc[v][11]);
                float zi = __builtin_amdgcn_rcpf(pz);
                float sx = px * zi, sy = py * zi;
                float sny = rintf(sy);
                sy = (fabsf(sy - sny) < 1e-4f) ? sny : sy;
                float y0f = floorf(sy);
                float wy1 = sy - y0f, wy0 = 1.f - wy1;
                int yi0 = (int)y0f, yi1 = yi0 + 1;
                float ay0 = ((unsigned)yi0 < HH) ? wy0 : 0.f;
                float ay1 = ((unsigned)yi1 < HH) ? wy1 : 0.f;
                int yc0 = min(max(yi0, 0), HH-1);
                int yc1 = min(max(yi1, 0), HH-1);
                int r0 = yc0*WW, r1 = yc1*WW;
                const float* vbv = featT + (size_t)(((v+1)*BB + b)*HWp)*CC;
                float acc = tap_blend(vbv, sub8, sx, ay0, ay1, r0, r1, rva, rvb);
                acc += __shfl_xor(acc, 1);
                acc += __shfl_xor(acc, 2);
                if (sub == 0) SIMG(v, dB, kpix) = acc * (1.f/(float)CC);
            }
        }
        __syncthreads();

        int p8 = t >> 5;
        int d2 = t & 31;
        #pragma unroll
        for (int pi = 0; pi < PX/8; pi++) {
            int pidx = pi*8 + p8;
            mlp_out(SIMG(0, d2, pidx), SIMG(1, d2, pidx),
                    SIMG(2, d2, pidx), SIMG(3, d2, pidx),
                    d2, b, pbase + pidx, tabL, Tg, prm, out, simout);
        }
    }
}

// ---------------- fused 3x3x3 conv + softmax/argmax ----------------
__global__ __launch_bounds__(256) void convsm_kernel(
    const float* __restrict__ sim, const float* __restrict__ rw,
    const float* __restrict__ rb, const float* __restrict__ depthv,
    float* __restrict__ out) {
    __shared__ float tile[34*121 + 7];
    int t = threadIdx.x;
    int tw = blockIdx.x * 8;
    int th = blockIdx.y * 8;
    int b  = blockIdx.z;

    for (int i = t; i < 34*120; i += 256) {
        int e = i / 120; int rem = i % 120;
        int h = rem / 12, w = rem % 12;
        int gd = e - 1, gh = th + h - 1, gw = tw + w - 1;
        float v = 0.f;
        if (w < 10 && gd >= 0 && gd < DD && (unsigned)gh < HH && (unsigned)gw < WW)
            v = sim[((b*DD + gd)*HH + gh)*WW + gw];
        tile[e*121 + rem] = v;
    }
    __syncthreads();

    float wk[27];
    #pragma unroll
    for (int i = 0; i < 27; i++) wk[i] = rw[i];
    float bias = rb[0];

    int p  = t >> 2, dq = t & 3;
    int ph = p >> 3, pw = p & 7;
    int d0 = dq * 8;

    float cost[8];
    #pragma unroll
    for (int j = 0; j < 8; j++) cost[j] = bias;
    #pragma unroll
    for (int e = 0; e < 10; e++) {
        int el = d0 + e;
        float s0 = 0.f, s1 = 0.f, s2 = 0.f;
        #pragma unroll
        for (int kh = 0; kh < 3; kh++) {
            #pragma unroll
            for (int kw = 0; kw < 3; kw++) {
                float x = tile[el*121 + (ph+kh)*12 + (pw+kw)];
                s0 = fmaf(wk[0*9 + kh*3 + kw], x, s0);
                s1 = fmaf(wk[1*9 + kh*3 + kw], x, s1);
                s2 = fmaf(wk[2*9 + kh*3 + kw], x, s2);
            }
        }
        if (e < 8)            cost[e]   += s0;
        if (e >= 1 && e <= 8) cost[e-1] += s1;
        if (e >= 2)           cost[e-2] += s2;
    }

    int pg = (th + ph)*WW + (tw + pw);
    #pragma unroll
    for (int j = 0; j < 8; j++)
        out[OUT_COST + (b*DD + d0 + j)*HWp + pg] = cost[j];

    float m = cost[0]; int mi = d0;
    #pragma unroll
    for (int j = 1; j < 8; j++) { if (cost[j] > m) { m = cost[j]; mi = d0 + j; } }
    #pragma unroll
    for (int off = 1; off <= 2; off <<= 1) {
        float m2 = __shfl_xor(m, off);
        int  i2 = __shfl_xor(mi, off);
        if (m2 > m || (m2 == m && i2 < mi)) { m = m2; mi = i2; }
    }
    float sum = 0.f;
    float e8[8];
    #pragma unroll
    for (int j = 0; j < 8; j++) { e8[j] = __expf(cost[j] - m); sum += e8[j]; }
    #pragma unroll
    for (int off = 1; off <= 2; off <<= 1) sum += __shfl_xor(sum, off);
    float inv = 1.f / sum;
    #pragma unroll
    for (int j = 0; j < 8; j++)
        out[OUT_PROB + (b*DD + d0 + j)*HWp + pg] = e8[j] * inv;
    if (dq == 0) {
        out[OUT_DEPTH + b*HWp + pg] = depthv[(b*DD + mi)*HWp + pg];
        out[OUT_CONF  + b*HWp + pg] = inv;
    }
}

extern "C" void kernel_launch(void* const* d_in, const int* in_sizes, int n_in,
                              void* d_out, int out_size, void* d_ws, size_t ws_size,
                              hipStream_t stream) {
    const float* features = (const float*)d_in[0];
    const float* proj     = (const float*)d_in[1];
    const float* depthv   = (const float*)d_in[2];
    const float* w0 = (const float*)d_in[4];
    const float* g0 = (const float*)d_in[5];
    const float* b0 = (const float*)d_in[6];
    const float* m0 = (const float*)d_in[7];
    const float* v0 = (const float*)d_in[8];
    const float* w1 = (const float*)d_in[9];
    const float* g1 = (const float*)d_in[10];
    const float* b1 = (const float*)d_in[11];
    const float* m1 = (const float*)d_in[12];
    const float* v1 = (const float*)d_in[13];
    const float* w2 = (const float*)d_in[14];
    const float* b2 = (const float*)d_in[15];
    const float* rw = (const float*)d_in[16];
    const float* rb = (const float*)d_in[17];
    float* out = (float*)d_out;
    float* ws  = (float*)d_ws;

    transpose_setup_kernel<<<VV*BB*HWp/256, 256, 0, stream>>>(
        features, ws + OFF_FEAT, proj,
        w0, g0, b0, m0, v0, w1, g1, b1, m1, v1, w2, b2, ws);

    fused_sim_kernel<<<dim3(HWp/PX, BB), 256, 0, stream>>>(
        ws + OFF_FEAT, ws + OFF_RT, ws + OFF_PRM, ws + OFF_T, ws + OFF_TAB,
        ws + OFF_FLAG, depthv, ws + OFF_SIM, out);

    convsm_kernel<<<dim3(WW/8, HH/8, BB), 256, 0, stream>>>(
        ws + OFF_SIM, rw, rb, depthv, out);
}

// Round 21
// 72.062 us; speedup vs baseline: 1.2169x; 1.0659x over previous
//
#include <hip/hip_runtime.h>
#include <math.h>

#define BB 2
#define VV 5
#define CC 32
#define HH 128
#define WW 160
#define DD 32
#define HWp (HH*WW)          // 20480
#define NV (VV-1)            // 4 src views
#define PX 16                // pixels per block (divides WW)
#define MAXSLOT 18           // max x-table entries per (pixel,view)
#define UWMAX 30             // max union-column width per view (bx span 15 + dspread ~9.3 + 2)

// ---- workspace float offsets ----
#define OFF_RT   0                                   // B*NV*12 = 96
#define OFF_PRM  96                                  // 177 net params
#define OFF_FEAT 512                                 // f32 features V*B*HW*C
#define OFF_SIM  (OFF_FEAT + VV*BB*HWp*CC)           // B*D*HW similarity
#define OFF_T    (OFF_SIM + BB*DD*HWp)               // 16 sorted kinks
#define OFF_TAB  (OFF_T + 16)                        // 17*16 segment table
#define OFF_FLAG (OFF_TAB + 17*16)                   // BB fast-geometry flags

// ---- output float offsets ----
#define OUT_DEPTH 0
#define OUT_CONF  (BB*HWp)
#define OUT_PROB  (2*BB*HWp)
#define OUT_COST  (OUT_PROB + BB*DD*HWp)
#define OUT_VW    (OUT_COST + BB*DD*HWp)

// ---- fused_sim LDS union layout (floats into smemU[7056]) ----
#define ZI(d,k)     smemU[(d)*17 + (k)]
#define DEP(d,k)    smemU[(d)*17 + (k)]
#define REF(p,c)    smemU[544 + (p)*36 + (c)]
#define GT(v,p,i)   smemU[1120 + ((v)*16 + (p))*18 + (i)]
#define AY0(v,p)    smemU[2272 + (v)*16 + (p)]
#define AY1(v,p)    smemU[2336 + (v)*16 + (p)]
#define IR0(v,p)    smemI[2400 + (v)*16 + (p)]
#define IR1(v,p)    smemI[2464 + (v)*16 + (p)]
#define IXB(v,p)    smemI[2528 + (v)*16 + (p)]
#define ISL(v,p)    smemI[2592 + (v)*16 + (p)]
#define BADF        smemI[2656]
#define SIMG(v,d,p) smemU[544 + (((v)*32 + (d))*17 + (p))]
// union-column staging: stride 36 floats (144 B, 16B-aligned -> b128 LDS reads)
#define COLU(v,ux,c) smemU[2720 + (v)*(UWMAX*36) + (ux)*36 + (c)]
#define UOKI(v)     smemI[7040 + (v)]
#define UXLOI(v)    smemI[7044 + (v)]
#define UWI(v)      smemI[7048 + (v)]

// ---------------- setup body (runs in block 0 of transpose kernel) ----------
__device__ void build_proj(const float* proj, int b, int v, double M[4][4]) {
    const float* E = proj + (((b*VV + v)*2 + 0)*16);
    const float* K = proj + (((b*VV + v)*2 + 1)*16);
    for (int r = 0; r < 3; r++)
        for (int c = 0; c < 4; c++) {
            double s = 0.0;
            for (int k = 0; k < 3; k++) s += (double)K[r*4+k] * (double)E[k*4+c];
            M[r][c] = s;
        }
    for (int c = 0; c < 4; c++) M[3][c] = (double)E[12+c];
}

__device__ void inv4(const double M[4][4], double out[4][4]) {
    double a[4][8];
    for (int i = 0; i < 4; i++)
        for (int j = 0; j < 4; j++) { a[i][j] = M[i][j]; a[i][4+j] = (i == j) ? 1.0 : 0.0; }
    for (int col = 0; col < 4; col++) {
        int piv = col; double best = fabs(a[col][col]);
        for (int r = col+1; r < 4; r++) if (fabs(a[r][col]) > best) { best = fabs(a[r][col]); piv = r; }
        if (piv != col) for (int j = 0; j < 8; j++) { double t = a[col][j]; a[col][j] = a[piv][j]; a[piv][j] = t; }
        double dinv = 1.0 / a[col][col];
        for (int j = 0; j < 8; j++) a[col][j] *= dinv;
        for (int r = 0; r < 4; r++) {
            if (r == col) continue;
            double f = a[r][col];
            for (int j = 0; j < 8; j++) a[r][j] -= f * a[col][j];
        }
    }
    for (int i = 0; i < 4; i++) for (int j = 0; j < 4; j++) out[i][j] = a[i][4+j];
}

__device__ void setup_body(const float* __restrict__ proj,
    const float* __restrict__ w0, const float* __restrict__ g0, const float* __restrict__ b0,
    const float* __restrict__ m0, const float* __restrict__ v0,
    const float* __restrict__ w1, const float* __restrict__ g1, const float* __restrict__ b1,
    const float* __restrict__ m1, const float* __restrict__ v1,
    const float* __restrict__ w2, const float* __restrict__ b2,
    float* __restrict__ ws, int t,
    float* __restrict__ prmL, float* __restrict__ TL) {

    if (t < BB*NV) {
        int b = t / NV, v = 1 + (t % NV);
        double refM[4][4], inv[4][4], S[4][4];
        build_proj(proj, b, 0, refM);
        inv4(refM, inv);
        build_proj(proj, b, v, S);
        float* rt = ws + OFF_RT + (b*NV + (v-1))*12;
        for (int r = 0; r < 3; r++) {
            for (int c = 0; c < 3; c++) {
                double s = 0.0;
                for (int k = 0; k < 4; k++) s += S[r][k] * inv[k][c];
                rt[r*3 + c] = (float)s;
            }
            double s = 0.0;
            for (int k = 0; k < 4; k++) s += S[r][k] * inv[k][3];
            rt[9 + r] = (float)s;
        }
    }

    if (t < 16) {
        float sc = g0[t] / sqrtf(v0[t] + 1e-5f);
        prmL[t]      = w0[t] * sc;
        prmL[16 + t] = b0[t] - m0[t] * sc;
    }
    if (t >= 32 && t < 160) {
        int i = t - 32, q = i >> 4, o = i & 15;
        float sc = g1[q] / sqrtf(v1[q] + 1e-5f);
        prmL[32 + q*16 + o] = w1[q*16 + o] * sc;
    }
    if (t >= 160 && t < 168) {
        int q = t - 160;
        float sc = g1[q] / sqrtf(v1[q] + 1e-5f);
        prmL[160 + q] = b1[q] - m1[q] * sc;
        prmL[168 + q] = w2[q];
    }
    if (t == 176) prmL[176] = b2[0];
    __syncthreads();

    // fast-geometry detection (pz = depth, sy depth-independent)
    if (t < BB) {
        int ok = 1;
        for (int i = 0; i < NV; i++) {
            const float* ri = ws + OFF_RT + (t*NV + i)*12;
            ok &= (fabsf(ri[6])        < 1e-6f);
            ok &= (fabsf(ri[7])        < 1e-6f);
            ok &= (fabsf(ri[8] - 1.f)  < 1e-6f);
            ok &= (fabsf(ri[10])       < 1e-6f);
            ok &= (fabsf(ri[11])       < 1e-6f);
        }
        ws[OFF_FLAG + t] = ok ? 1.f : 0.f;
    }

    if (t == 0) {
        float tmp[16]; int nk = 0;
        for (int o = 0; o < 16; o++) {
            float a = prmL[o];
            if (a != 0.f) tmp[nk++] = -prmL[16+o] / a;
        }
        for (int i = 1; i < nk; i++) {
            float key = tmp[i]; int j = i-1;
            while (j >= 0 && tmp[j] > key) { tmp[j+1] = tmp[j]; j--; }
            tmp[j+1] = key;
        }
        for (int i = 0; i < 16; i++) TL[i] = (i < nk) ? tmp[i] : 3.4e38f;
    }
    __syncthreads();

    if (t < 17*8) {
        int seg = t >> 3, q = t & 7;
        float lo = (seg == 0)  ? -1e30f : TL[seg-1];
        float hi = (seg == 16) ?  1e30f : TL[seg];
        float smid;
        if (hi > 1e29f)       smid = lo + 1.f;
        else if (lo < -1e29f) smid = hi - 1.f;
        else                  smid = 0.5f*(lo + hi);
        float alpha = 0.f, beta = prmL[160+q];
        #pragma unroll
        for (int o = 0; o < 16; o++) {
            float a = prmL[o], c = prmL[16+o];
            if (a*smid + c > 0.f) {
                alpha += prmL[32+q*16+o]*a;
                beta  += prmL[32+q*16+o]*c;
            }
        }
        ws[OFF_TAB + seg*16 + q]     = alpha;
        ws[OFF_TAB + seg*16 + 8 + q] = beta;
    }
    if (t < 177) ws[OFF_PRM + t] = prmL[t];
    if (t < 16)  ws[OFF_T + t]   = TL[t];
}

// ---------------- transpose (+ setup in block 0) ----------------
__global__ __launch_bounds__(256) void transpose_setup_kernel(
    const float* __restrict__ fea, float* __restrict__ featT,
    const float* __restrict__ proj,
    const float* __restrict__ w0, const float* __restrict__ g0, const float* __restrict__ b0,
    const float* __restrict__ m0, const float* __restrict__ v0,
    const float* __restrict__ w1, const float* __restrict__ g1, const float* __restrict__ b1,
    const float* __restrict__ m1, const float* __restrict__ v1,
    const float* __restrict__ w2, const float* __restrict__ b2,
    float* __restrict__ ws) {
    __shared__ float prmL[177];
    __shared__ float TL[16];
    if (blockIdx.x == 0)
        setup_body(proj, w0, g0, b0, m0, v0, w1, g1, b1, m1, v1, w2, b2,
                   ws, threadIdx.x, prmL, TL);

    int t = blockIdx.x*256 + threadIdx.x;        // V*B*H*W
    int w = t % WW;
    int h = (t / WW) % HH;
    int b = (t / (WW*HH)) % BB;
    int v = t / (WW*HH*BB);
    const float* src = fea + (size_t)((v*BB + b)*CC) * HWp + h*WW + w;
    float* dst = featT + (size_t)((v*BB + b)*HWp + h*WW + w) * CC;
    #pragma unroll
    for (int c = 0; c < CC; c += 4) {
        float4 q;
        q.x = src[(c+0)*HWp];
        q.y = src[(c+1)*HWp];
        q.z = src[(c+2)*HWp];
        q.w = src[(c+3)*HWp];
        *reinterpret_cast<float4*>(dst + c) = q;
    }
}

__device__ __forceinline__ float half_max(float v) {
    v = fmaxf(v, __shfl_xor(v, 1));
    v = fmaxf(v, __shfl_xor(v, 2));
    v = fmaxf(v, __shfl_xor(v, 4));
    v = fmaxf(v, __shfl_xor(v, 8));
    v = fmaxf(v, __shfl_xor(v, 16));
    return v;
}

__device__ __forceinline__ float dot32(const float* __restrict__ col,
                                       const float* __restrict__ refp) {
    float acc = 0.f;
    #pragma unroll
    for (int c = 0; c < CC; c += 4) {
        float4 a = *reinterpret_cast<const float4*>(col + c);
        float4 r = *reinterpret_cast<const float4*>(refp + c);
        acc = fmaf(a.w, r.w, fmaf(a.z, r.z, fmaf(a.y, r.y, fmaf(a.x, r.x, acc))));
    }
    return acc;
}

// LDS-source dot: 16B-aligned (stride-36 layout) -> b128 LDS reads, identical
// FMA nesting order (bitwise same result as dot32).
__device__ __forceinline__ float dot32_lds(const float* __restrict__ col,
                                           const float* __restrict__ refp) {
    float acc = 0.f;
    #pragma unroll
    for (int c = 0; c < CC; c += 4) {
        float4 a = *reinterpret_cast<const float4*>(col + c);
        float4 r = *reinterpret_cast<const float4*>(refp + c);
        acc = fmaf(a.w, r.w, fmaf(a.z, r.z, fmaf(a.y, r.y, fmaf(a.x, r.x, acc))));
    }
    return acc;
}

// phase-B body (lane layout: d2 = lane&31): 17x16 seg-table MLP
__device__ __forceinline__ void mlp_out(
    float s0, float s1, float s2, float s3,
    int d2, int b, int p,
    const float* __restrict__ tabL, const float* __restrict__ Tg,
    const float* __restrict__ prm,
    float* __restrict__ out, float* __restrict__ simout) {
    float T0 = Tg[0], T1 = Tg[1], T2 = Tg[2], T3 = Tg[3];
    float T4 = Tg[4], T5 = Tg[5], T6 = Tg[6], T7 = Tg[7];
    float T8 = Tg[8], T9 = Tg[9], T10 = Tg[10], T11 = Tg[11];
    float T12 = Tg[12], T13 = Tg[13], T14 = Tg[14], T15 = Tg[15];
    float wq0 = prm[168], wq1 = prm[169], wq2 = prm[170], wq3 = prm[171];
    float wq4 = prm[172], wq5 = prm[173], wq6 = prm[174], wq7 = prm[175];
    float p176 = prm[176];

    float sv[NV] = {s0, s1, s2, s3};
    float vw[NV];
    #pragma unroll
    for (int v = 0; v < NV; v++) {
        float s = sv[v];
        int seg = 0;
        seg += (s > T0);  seg += (s > T1);  seg += (s > T2);  seg += (s > T3);
        seg += (s > T4);  seg += (s > T5);  seg += (s > T6);  seg += (s > T7);
        seg += (s > T8);  seg += (s > T9);  seg += (s > T10); seg += (s > T11);
        seg += (s > T12); seg += (s > T13); seg += (s > T14); seg += (s > T15);
        const float* row = &tabL[seg << 4];
        float4 A0 = *reinterpret_cast<const float4*>(row);
        float4 A1 = *reinterpret_cast<const float4*>(row + 4);
        float4 B0 = *reinterpret_cast<const float4*>(row + 8);
        float4 B1 = *reinterpret_cast<const float4*>(row + 12);
        float h2v = p176;
        h2v = fmaf(wq0, fmaxf(fmaf(A0.x, s, B0.x), 0.f), h2v);
        h2v = fmaf(wq1, fmaxf(fmaf(A0.y, s, B0.y), 0.f), h2v);
        h2v = fmaf(wq2, fmaxf(fmaf(A0.z, s, B0.z), 0.f), h2v);
        h2v = fmaf(wq3, fmaxf(fmaf(A0.w, s, B0.w), 0.f), h2v);
        h2v = fmaf(wq4, fmaxf(fmaf(A1.x, s, B1.x), 0.f), h2v);
        h2v = fmaf(wq5, fmaxf(fmaf(A1.y, s, B1.y), 0.f), h2v);
        h2v = fmaf(wq6, fmaxf(fmaf(A1.z, s, B1.z), 0.f), h2v);
        h2v = fmaf(wq7, fmaxf(fmaf(A1.w, s, B1.w), 0.f), h2v);
        float m = half_max(h2v);
        vw[v] = 1.f/(1.f + __expf(-m));
    }

    if (d2 == 0) out[OUT_VW + (b*NV + 0)*HWp + p] = vw[0];
    if (d2 == 1) out[OUT_VW + (b*NV + 1)*HWp + p] = vw[1];
    if (d2 == 2) out[OUT_VW + (b*NV + 2)*HWp + p] = vw[2];
    if (d2 == 3) out[OUT_VW + (b*NV + 3)*HWp + p] = vw[3];

    float wsum = 1e-5f + vw[0] + vw[1] + vw[2] + vw[3];
    float ssum = s0*vw[0] + s1*vw[1] + s2*vw[2] + s3*vw[3];
    simout[(b*DD + d2)*HWp + p] = ssum / wsum;
}

// general-path x-side tap pair
__device__ __forceinline__ float tap_blend(
    const float* __restrict__ vbv, int sub8, float sx,
    float ay0, float ay1, int r0, int r1,
    float4 rva, float4 rvb) {
    float x0f = floorf(sx);
    float wx1 = sx - x0f;
    float wx0 = 1.f - wx1;
    int xi0 = (int)x0f, xi1 = xi0 + 1;
    float ax0 = ((unsigned)xi0 < WW) ? wx0 : 0.f;
    float ax1 = ((unsigned)xi1 < WW) ? wx1 : 0.f;
    int xc0 = min(max(xi0, 0), WW-1);
    int xc1 = min(max(xi1, 0), WW-1);
    float w00 = ax0*ay0, w01 = ax1*ay0;
    const float* q00 = vbv + (((r0 + xc0) << 5) + sub8);
    const float* q01 = vbv + (((r0 + xc1) << 5) + sub8);
    float4 t00a = *reinterpret_cast<const float4*>(q00);
    float4 t00b = *reinterpret_cast<const float4*>(q00 + 4);
    float4 t01a = *reinterpret_cast<const float4*>(q01);
    float4 t01b = *reinterpret_cast<const float4*>(q01 + 4);

    float blx = fmaf(w01, t01a.x, w00*t00a.x);
    float bly = fmaf(w01, t01a.y, w00*t00a.y);
    float blz = fmaf(w01, t01a.z, w00*t00a.z);
    float blw = fmaf(w01, t01a.w, w00*t00a.w);
    float acc = fmaf(rva.w,blw, fmaf(rva.z,blz, fmaf(rva.y,bly, rva.x*blx)));
    blx = fmaf(w01, t01b.x, w00*t00b.x);
    bly = fmaf(w01, t01b.y, w00*t00b.y);
    blz = fmaf(w01, t01b.z, w00*t00b.z);
    blw = fmaf(w01, t01b.w, w00*t00b.w);
    acc = fmaf(rvb.w,blw, fmaf(rvb.z,blz, fmaf(rvb.y,bly, fmaf(rvb.x,blx, acc))));

    if (ay1 != 0.f) {
        float w10 = ax0*ay1, w11 = ax1*ay1;
        const float* q10 = vbv + (((r1 + xc0) << 5) + sub8);
        const float* q11 = vbv + (((r1 + xc1) << 5) + sub8);
        float4 t10a = *reinterpret_cast<const float4*>(q10);
        float4 t10b = *reinterpret_cast<const float4*>(q10 + 4);
        float4 t11a = *reinterpret_cast<const float4*>(q11);
        float4 t11b = *reinterpret_cast<const float4*>(q11 + 4);
        float cx = fmaf(w11, t11a.x, w10*t10a.x);
        float cy = fmaf(w11, t11a.y, w10*t10a.y);
        float cz = fmaf(w11, t11a.z, w10*t10a.z);
        float cw = fmaf(w11, t11a.w, w10*t10a.w);
        acc = fmaf(rva.w,cw, fmaf(rva.z,cz, fmaf(rva.y,cy, fmaf(rva.x,cx, acc))));
        cx = fmaf(w11, t11b.x, w10*t10b.x);
        cy = fmaf(w11, t11b.y, w10*t10b.y);
        cz = fmaf(w11, t11b.z, w10*t10b.z);
        cw = fmaf(w11, t11b.w, w10*t10b.w);
        acc = fmaf(rvb.w,cw, fmaf(rvb.z,cz, fmaf(rvb.y,cy, fmaf(rvb.x,cx, acc))));
    }
    return acc;
}

// ---------------- fused warp + sim + PWL-MLP + view aggregation ----------------
__global__ __launch_bounds__(256) void fused_sim_kernel(
    const float* __restrict__ featT, const float* __restrict__ rtAll,
    const float* __restrict__ prm, const float* __restrict__ Tg,
    const float* __restrict__ tabG, const float* __restrict__ flagG,
    const float* __restrict__ depthv,
    float* __restrict__ simout, float* __restrict__ out) {
    __shared__ __align__(16) float smemU[7056];   // union region (~28 KB)
    __shared__ __align__(16) float tabL[17*16];
    int* smemI = (int*)smemU;

    int t = threadIdx.x;
    int b = blockIdx.y;
    int pbase = blockIdx.x * PX;
    int hi  = pbase / WW;
    int wi0 = pbase % WW;
    float fy = (float)hi;

    bool fast = (flagG[b] != 0.f);   // block-uniform

    // ---- staging ----
    {
        int di = t >> 4, k = t & 15;
        float dep0 = depthv[(b*DD + di)*HWp + pbase + k];
        float dep1 = depthv[(b*DD + di + 16)*HWp + pbase + k];
        if (fast) {
            ZI(di, k)    = __builtin_amdgcn_rcpf(dep0);
            ZI(di+16, k) = __builtin_amdgcn_rcpf(dep1);
            if (t < 128) {      // ref features via float4: p = t>>3, c4 = (t&7)*4
                int p = t >> 3, c4 = (t & 7) * 4;
                float4 rq = *reinterpret_cast<const float4*>(
                    featT + (size_t)(b*HWp + pbase + p)*CC + c4);
                *reinterpret_cast<float4*>(&REF(p, c4)) = rq;
            }
        } else {
            DEP(di, k)    = dep0;
            DEP(di+16, k) = dep1;
        }
        tabL[t] = tabG[t];
        if (t < 16) tabL[256 + t] = tabG[256 + t];
        if (t == 0 && fast) BADF = 0;
    }
    __syncthreads();

    float rc[NV][12];
    #pragma unroll
    for (int v = 0; v < NV; v++)
        #pragma unroll
        for (int j = 0; j < 12; j++)
            rc[v][j] = rtAll[(b*NV + v)*12 + j];
    float bx0[NV], by0[NV], bz0[NV];
    #pragma unroll
    for (int v = 0; v < NV; v++) {
        bx0[v] = fmaf((float)wi0, rc[v][0], fmaf(fy, rc[v][1], rc[v][2]));
        by0[v] = fmaf((float)wi0, rc[v][3], fmaf(fy, rc[v][4], rc[v][5]));
        bz0[v] = fmaf((float)wi0, rc[v][6], fmaf(fy, rc[v][7], rc[v][8]));
    }

    bool needRestage = false;
    if (fast) {
        // ---- step 1: zi-range once per pixel-phase; per-view range analytic ----
        int p_loc = t >> 5, d = t & 31;
        for (int ph = 0; ph < 2; ph++) {
            int p = ph*8 + p_loc;
            float zi = ZI(d, p);
            float mnz = zi, mxz = zi;
            #pragma unroll
            for (int off = 1; off <= 16; off <<= 1) {
                mnz = fminf(mnz, __shfl_xor(mnz, off));
                mxz = fmaxf(mxz, __shfl_xor(mxz, off));
            }
            if (d == 0) {
                float fk = (float)p;
                #pragma unroll
                for (int v = 0; v < NV; v++) {
                    float bx = fmaf(fk, rc[v][0], bx0[v]);
                    float t0c = rc[v][9];
                    float sxa = fmaf(t0c, mnz, bx);
                    float sxb = fmaf(t0c, mxz, bx);
                    float mn = fminf(sxa, sxb), mx = fmaxf(sxa, sxb);
                    float by = fmaf(fk, rc[v][3], by0[v]);
                    float sy = by;
                    float sny = rintf(sy);
                    sy = (fabsf(sy - sny) < 1e-4f) ? sny : sy;
                    float y0f = floorf(sy);
                    float wy1 = sy - y0f, wy0 = 1.f - wy1;
                    int yi0 = (int)y0f, yi1 = yi0 + 1;
                    AY0(v, p) = ((unsigned)yi0 < HH) ? wy0 : 0.f;
                    AY1(v, p) = ((unsigned)yi1 < HH) ? wy1 : 0.f;
                    IR0(v, p) = min(max(yi0, 0), HH-1)*WW;
                    IR1(v, p) = min(max(yi1, 0), HH-1)*WW;
                    bool finite = (mn > -1e9f) && (mx < 1e9f) && (mn == mn) && (mx == mx);
                    int xb = finite ? (int)floorf(mn) : 0;
                    int slots = finite ? ((int)floorf(mx) - xb + 2) : MAXSLOT + 1;
                    IXB(v, p) = xb;
                    ISL(v, p) = slots;
                    if (slots > MAXSLOT) BADF = 1;
                }
            }
        }
        __syncthreads();
        if (BADF) { fast = false; needRestage = true; }
    }

    bool uni = false;
    if (fast) {
        // ---- step 1.5: uniform-row + union-range detection (wave 0) ----
        if (t < 64) {
            int v = t >> 4, p = t & 15;
            int ok = (AY1(v, p) == 0.f) && (IR0(v, p) == IR0(v, 0)) ? 1 : 0;
            int xlo = IXB(v, p);
            int xhi = xlo + ISL(v, p) - 1;
            #pragma unroll
            for (int off = 1; off <= 8; off <<= 1) {
                ok  &= __shfl_xor(ok, off);
                xlo  = min(xlo, __shfl_xor(xlo, off));
                xhi  = max(xhi, __shfl_xor(xhi, off));
            }
            if (p == 0) {
                int wdt = xhi - xlo + 1;
                UOKI(v)  = (ok && wdt <= UWMAX) ? 1 : 0;
                UXLOI(v) = xlo;
                UWI(v)   = wdt;
            }
        }
        __syncthreads();
        uni = UOKI(0) && UOKI(1) && UOKI(2) && UOKI(3);
    }

    if (fast) {
        if (uni) {
            // ---- step 2a: coalesced union-column staging, all views ----
            for (int i = t; i < NV*UWMAX*8; i += 256) {
                int v  = i / (UWMAX*8);
                int rem = i - v*(UWMAX*8);
                int ux = rem >> 3, c4 = (rem & 7) * 4;
                if (ux < UWI(v)) {
                    int xc = min(max(UXLOI(v) + ux, 0), WW-1);
                    int r0 = IR0(v, 0);
                    const float* src = featT + (size_t)(((v+1)*BB + b)*HWp)*CC
                                       + ((r0 + xc) << 5) + c4;
                    float4 q = *reinterpret_cast<const float4*>(src);
                    *reinterpret_cast<float4*>(&COLU(v, ux, c4)) = q;
                }
            }
            __syncthreads();
            // ---- step 2b: dot tables from LDS (ay1 == 0 in uni mode) ----
            {
                int v2 = t & 3, p2 = (t >> 2) & 15, i0 = t >> 6;
                float ay0 = AY0(v2, p2);
                int xb = IXB(v2, p2), slots = ISL(v2, p2);
                int xoff = xb - UXLOI(v2);
                const float* refp = &REF(p2, 0);
                for (int i2 = i0; i2 < slots; i2 += 4) {
                    const float* col = &COLU(v2, xoff + i2, 0);
                    float g = ay0 * dot32_lds(col, refp);
                    GT(v2, p2, i2) = g * (1.f/(float)CC);
                }
            }
            __syncthreads();
        } else {
            // ---- step 2 (global fallback): all-view dot tables ----
            {
                int v2 = t & 3, p2 = (t >> 2) & 15, i0 = t >> 6;
                float ay0 = AY0(v2, p2), ay1 = AY1(v2, p2);
                int r0 = IR0(v2, p2), r1 = IR1(v2, p2);
                int xb = IXB(v2, p2), slots = ISL(v2, p2);
                const float* vbv = featT + (size_t)(((v2+1)*BB + b)*HWp)*CC;
                const float* refp = &REF(p2, 0);
                for (int i2 = i0; i2 < slots; i2 += 4) {
                    int xc = min(max(xb + i2, 0), WW-1);
                    float g = ay0 * dot32(vbv + ((r0 + xc) << 5), refp);
                    if (ay1 != 0.f) g = fmaf(ay1, dot32(vbv + ((r1 + xc) << 5), refp), g);
                    GT(v2, p2, i2) = g * (1.f/(float)CC);
                }
            }
            __syncthreads();
        }
        // ---- step 3 fused with phase B ----
        {
            int p_loc = t >> 5, d = t & 31;
            for (int ph = 0; ph < 2; ph++) {
                int p = ph*8 + p_loc;
                float fk = (float)p;
                float zi = ZI(d, p);
                float sv[NV];
                #pragma unroll
                for (int v = 0; v < NV; v++) {
                    float bx = fmaf(fk, rc[v][0], bx0[v]);
                    float sx = fmaf(rc[v][9], zi, bx);
                    float x0f = floorf(sx);
                    float wx1 = sx - x0f, wx0 = 1.f - wx1;
                    int xi0 = (int)x0f, xi1 = xi0 + 1;
                    float ax0 = ((unsigned)xi0 < WW) ? wx0 : 0.f;
                    float ax1 = ((unsigned)xi1 < WW) ? wx1 : 0.f;
                    int ii = xi0 - IXB(v, p);
                    float g0 = GT(v, p, ii);
                    float g1 = GT(v, p, ii+1);
                    sv[v] = fmaf(ax0, g0, ax1*g1);
                }
                mlp_out(sv[0], sv[1], sv[2], sv[3], d, b, pbase + p,
                        tabL, Tg, prm, out, simout);
            }
        }
        return;
    }

    // ---------------- general path ----------------
    if (needRestage) {
        int di = t >> 4, k = t & 15;
        DEP(di, k)    = depthv[(b*DD + di)*HWp + pbase + k];
        DEP(di+16, k) = depthv[(b*DD + di + 16)*HWp + pbase + k];
        __syncthreads();
    }
    {
        int sub = t & 3;
        int dB  = (t >> 2) & 31;
        int kk  = t >> 7;
        int sub8 = sub*8;
        #pragma unroll 2
        for (int j = 0; j < PX/2; j++) {
            int kpix = j*2 + kk;
            int p = pbase + kpix;
            float fk = (float)kpix;
            float depth = DEP(dB, kpix);
            const float* refp = featT + (size_t)(b*HWp + p)*CC + sub8;
            float4 rva = *reinterpret_cast<const float4*>(refp);
            float4 rvb = *reinterpret_cast<const float4*>(refp + 4);

            #pragma unroll
            for (int v = 0; v < NV; v++) {
                float bx = fmaf(fk, rc[v][0], bx0[v]);
                float by = fmaf(fk, rc[v][3], by0[v]);
                float bz = fmaf(fk, rc[v][6], bz0[v]);
                float px = fmaf(bx, depth, rc[v][9]);
                float py = fmaf(by, depth, rc[v][10]);
                float pz = fmaf(bz, depth, rc[v][11]);
                float zi = __builtin_amdgcn_rcpf(pz);
                float sx = px * zi, sy = py * zi;
                float sny = rintf(sy);
                sy = (fabsf(sy - sny) < 1e-4f) ? sny : sy;
                float y0f = floorf(sy);
                float wy1 = sy - y0f, wy0 = 1.f - wy1;
                int yi0 = (int)y0f, yi1 = yi0 + 1;
                float ay0 = ((unsigned)yi0 < HH) ? wy0 : 0.f;
                float ay1 = ((unsigned)yi1 < HH) ? wy1 : 0.f;
                int yc0 = min(max(yi0, 0), HH-1);
                int yc1 = min(max(yi1, 0), HH-1);
                int r0 = yc0*WW, r1 = yc1*WW;
                const float* vbv = featT + (size_t)(((v+1)*BB + b)*HWp)*CC;
                float acc = tap_blend(vbv, sub8, sx, ay0, ay1, r0, r1, rva, rvb);
                acc += __shfl_xor(acc, 1);
                acc += __shfl_xor(acc, 2);
                if (sub == 0) SIMG(v, dB, kpix) = acc * (1.f/(float)CC);
            }
        }
        __syncthreads();

        int p8 = t >> 5;
        int d2 = t & 31;
        #pragma unroll
        for (int pi = 0; pi < PX/8; pi++) {
            int pidx = pi*8 + p8;
            mlp_out(SIMG(0, d2, pidx), SIMG(1, d2, pidx),
                    SIMG(2, d2, pidx), SIMG(3, d2, pidx),
                    d2, b, pbase + pidx, tabL, Tg, prm, out, simout);
        }
    }
}

// ---------------- fused 3x3x3 conv + softmax/argmax ----------------
__global__ __launch_bounds__(256) void convsm_kernel(
    const float* __restrict__ sim, const float* __restrict__ rw,
    const float* __restrict__ rb, const float* __restrict__ depthv,
    float* __restrict__ out) {
    __shared__ float tile[34*121 + 7];
    int t = threadIdx.x;
    int tw = blockIdx.x * 8;
    int th = blockIdx.y * 8;
    int b  = blockIdx.z;

    for (int i = t; i < 34*120; i += 256) {
        int e = i / 120; int rem = i % 120;
        int h = rem / 12, w = rem % 12;
        int gd = e - 1, gh = th + h - 1, gw = tw + w - 1;
        float v = 0.f;
        if (w < 10 && gd >= 0 && gd < DD && (unsigned)gh < HH && (unsigned)gw < WW)
            v = sim[((b*DD + gd)*HH + gh)*WW + gw];
        tile[e*121 + rem] = v;
    }
    __syncthreads();

    float wk[27];
    #pragma unroll
    for (int i = 0; i < 27; i++) wk[i] = rw[i];
    float bias = rb[0];

    int p  = t >> 2, dq = t & 3;
    int ph = p >> 3, pw = p & 7;
    int d0 = dq * 8;

    float cost[8];
    #pragma unroll
    for (int j = 0; j < 8; j++) cost[j] = bias;
    #pragma unroll
    for (int e = 0; e < 10; e++) {
        int el = d0 + e;
        float s0 = 0.f, s1 = 0.f, s2 = 0.f;
        #pragma unroll
        for (int kh = 0; kh < 3; kh++) {
            #pragma unroll
            for (int kw = 0; kw < 3; kw++) {
                float x = tile[el*121 + (ph+kh)*12 + (pw+kw)];
                s0 = fmaf(wk[0*9 + kh*3 + kw], x, s0);
                s1 = fmaf(wk[1*9 + kh*3 + kw], x, s1);
                s2 = fmaf(wk[2*9 + kh*3 + kw], x, s2);
            }
        }
        if (e < 8)            cost[e]   += s0;
        if (e >= 1 && e <= 8) cost[e-1] += s1;
        if (e >= 2)           cost[e-2] += s2;
    }

    int pg = (th + ph)*WW + (tw + pw);
    #pragma unroll
    for (int j = 0; j < 8; j++)
        out[OUT_COST + (b*DD + d0 + j)*HWp + pg] = cost[j];

    float m = cost[0]; int mi = d0;
    #pragma unroll
    for (int j = 1; j < 8; j++) { if (cost[j] > m) { m = cost[j]; mi = d0 + j; } }
    #pragma unroll
    for (int off = 1; off <= 2; off <<= 1) {
        float m2 = __shfl_xor(m, off);
        int  i2 = __shfl_xor(mi, off);
        if (m2 > m || (m2 == m && i2 < mi)) { m = m2; mi = i2; }
    }
    float sum = 0.f;
    float e8[8];
    #pragma unroll
    for (int j = 0; j < 8; j++) { e8[j] = __expf(cost[j] - m); sum += e8[j]; }
    #pragma unroll
    for (int off = 1; off <= 2; off <<= 1) sum += __shfl_xor(sum, off);
    float inv = 1.f / sum;
    #pragma unroll
    for (int j = 0; j < 8; j++)
        out[OUT_PROB + (b*DD + d0 + j)*HWp + pg] = e8[j] * inv;
    if (dq == 0) {
        out[OUT_DEPTH + b*HWp + pg] = depthv[(b*DD + mi)*HWp + pg];
        out[OUT_CONF  + b*HWp + pg] = inv;
    }
}

extern "C" void kernel_launch(void* const* d_in, const int* in_sizes, int n_in,
                              void* d_out, int out_size, void* d_ws, size_t ws_size,
                              hipStream_t stream) {
    const float* features = (const float*)d_in[0];
    const float* proj     = (const float*)d_in[1];
    const float* depthv   = (const float*)d_in[2];
    const float* w0 = (const float*)d_in[4];
    const float* g0 = (const float*)d_in[5];
    const float* b0 = (const float*)d_in[6];
    const float* m0 = (const float*)d_in[7];
    const float* v0 = (const float*)d_in[8];
    const float* w1 = (const float*)d_in[9];
    const float* g1 = (const float*)d_in[10];
    const float* b1 = (const float*)d_in[11];
    const float* m1 = (const float*)d_in[12];
    const float* v1 = (const float*)d_in[13];
    const float* w2 = (const float*)d_in[14];
    const float* b2 = (const float*)d_in[15];
    const float* rw = (const float*)d_in[16];
    const float* rb = (const float*)d_in[17];
    float* out = (float*)d_out;
    float* ws  = (float*)d_ws;

    transpose_setup_kernel<<<VV*BB*HWp/256, 256, 0, stream>>>(
        features, ws + OFF_FEAT, proj,
        w0, g0, b0, m0, v0, w1, g1, b1, m1, v1, w2, b2, ws);

    fused_sim_kernel<<<dim3(HWp/PX, BB), 256, 0, stream>>>(
        ws + OFF_FEAT, ws + OFF_RT, ws + OFF_PRM, ws + OFF_T, ws + OFF_TAB,
        ws + OFF_FLAG, depthv, ws + OFF_SIM, out);

    convsm_kernel<<<dim3(WW/8, HH/8, BB), 256, 0, stream>>>(
        ws + OFF_SIM, rw, rb, depthv, out);
}